// Round 16
// baseline (1355.195 us; speedup 1.0000x reference)
//
#include <hip/hip_runtime.h>
#include <hip/hip_bf16.h>

// ---------------- problem constants ----------------
#define NN 500000
#define EE 1250000
#define NP 501760          // padded node count
#define NBLK 489           // scan blocks of 1024
#define PBLK 2048          // pooling blocks / private slots
#define PNPB 245           // nodes per pooling block (2048*245 = 501,760 >= NN)

typedef __attribute__((ext_vector_type(8))) short bf16x8;
typedef __attribute__((ext_vector_type(4))) float f32x4;

__device__ __forceinline__ float ngnn97_bf2f(unsigned short u) {
  return __uint_as_float(((unsigned int)u) << 16);
}
__device__ __forceinline__ unsigned short ngnn97_f2bf(float f) {
  union { __hip_bfloat16 b; unsigned short u; } cv;
  cv.b = __float2bfloat16(f);
  return cv.u;
}

// ---------------- diagnostic code writer (guard path only) ----------------
__global__ void ngnn97_code(float* __restrict__ out, float v) {
  if (threadIdx.x < 64) out[threadIdx.x] = v;
}

// ---------------- precompute folded weights (bf16, MFMA-B layout) + bf16 ztab ----------------
__global__ __launch_bounds__(256) void ngnn97_pre(
    const float* __restrict__ ggc, const float* __restrict__ wih,
    const float* __restrict__ whh, const float* __restrict__ bih,
    const float* __restrict__ bhh, const float* __restrict__ tfW,
    const float* __restrict__ ztab,
    unsigned short* __restrict__ Ubt, float* __restrict__ Ub,
    unsigned short* __restrict__ Vbt, unsigned short* __restrict__ ztabh) {
  int idx = blockIdx.x * 256 + threadIdx.x;
  if (idx < 163840) {                      // Ubt: 5*256*128
    int l = idx >> 15, r = idx & 32767;
    int n = r >> 7, k = r & 127;
    float v = 0.f;
    if (k < 64) {
      if (n < 192) {
        const float* gp = ggc + l * 4096 + k * 64;
        const float* wp = wih + l * 12288 + n * 64;
        float acc = 0.f;
#pragma unroll
        for (int t2 = 0; t2 < 64; t2++) acc = fmaf(gp[t2], wp[t2], acc);
        v = acc;
      }
    } else {
      int k2 = k - 64;
      if (n < 128) v = whh[l * 12288 + n * 64 + k2];
      else if (n >= 192) v = whh[l * 12288 + (n - 64) * 64 + k2];
    }
    Ubt[idx] = ngnn97_f2bf(v);
  } else if (idx < 196608) {               // Vbt: 4*64*128 (= tfW flat)
    int i2 = idx - 163840;
    Vbt[i2] = ngnn97_f2bf(tfW[i2]);
  } else if (idx < 197888) {               // Ub: 5*256
    int i2 = idx - 196608;
    int l = i2 >> 8, j = i2 & 255;
    float v;
    if (j < 128)      v = bih[l * 192 + j] + bhh[l * 192 + j];
    else if (j < 192) v = bih[l * 192 + j];
    else              v = bhh[l * 192 + j - 64];
    Ub[i2] = v;
  } else if (idx < 229888) {               // ztabh: 5*100*64 bf16
    int i2 = idx - 197888;
    ztabh[i2] = ngnn97_f2bf(ztab[i2]);
  }
}

// ---------------- CSR build ----------------
__global__ __launch_bounds__(256) void ngnn97_hist(const int* __restrict__ dst, int* __restrict__ counts) {
  int e = blockIdx.x * 256 + threadIdx.x;
  if (e < EE) atomicAdd(&counts[dst[e]], 1);
}

__global__ __launch_bounds__(256) void ngnn97_red(const int* __restrict__ counts, int* __restrict__ bsum) {
  __shared__ int s[256];
  int t = threadIdx.x, base = blockIdx.x * 1024;
  int v = 0;
#pragma unroll
  for (int i = 0; i < 4; i++) v += counts[base + t + i * 256];
  s[t] = v; __syncthreads();
  for (int o = 128; o > 0; o >>= 1) { if (t < o) s[t] += s[t + o]; __syncthreads(); }
  if (t == 0) bsum[blockIdx.x] = s[0];
}

__global__ __launch_bounds__(512) void ngnn97_scan1(const int* __restrict__ bsum, int* __restrict__ boff) {
  __shared__ int s[512];
  int t = threadIdx.x;
  int v = (t < NBLK) ? bsum[t] : 0;
  s[t] = v; __syncthreads();
  for (int o = 1; o < 512; o <<= 1) {
    int a = (t >= o) ? s[t - o] : 0;
    __syncthreads(); s[t] += a; __syncthreads();
  }
  if (t < NBLK) boff[t] = s[t] - v;   // exclusive
}

__global__ __launch_bounds__(256) void ngnn97_scan2(const int* __restrict__ counts, const int* __restrict__ boff,
                                                    int* __restrict__ row_ptr, int* __restrict__ cursor) {
  __shared__ int s[256];
  int t = threadIdx.x, base = blockIdx.x * 1024;
  int4 c = *(const int4*)(counts + base + t * 4);
  int tsum = c.x + c.y + c.z + c.w;
  s[t] = tsum; __syncthreads();
  for (int o = 1; o < 256; o <<= 1) {
    int a = (t >= o) ? s[t - o] : 0;
    __syncthreads(); s[t] += a; __syncthreads();
  }
  int off = boff[blockIdx.x] + s[t] - tsum;
  int4 r;
  r.x = off; r.y = off + c.x; r.z = off + c.x + c.y; r.w = off + c.x + c.y + c.z;
  *(int4*)(row_ptr + base + t * 4) = r;
  *(int4*)(cursor + base + t * 4) = r;
}

__global__ __launch_bounds__(256) void ngnn97_fill(const int* __restrict__ src, const int* __restrict__ dst,
                                                   int* __restrict__ cursor, int* __restrict__ srcs) {
  int e = blockIdx.x * 256 + threadIdx.x;
  if (e < EE) {
    int pos = atomicAdd(&cursor[dst[e]], 1);
    srcs[pos] = src[e];
  }
}

// ---------------- node -> graph id precompute (uint8) ----------------
__global__ __launch_bounds__(256) void ngnn97_g8(const int* __restrict__ n2s, const int* __restrict__ s2g,
                                                 unsigned char* __restrict__ g8) {
  int idx = blockIdx.x * 256 + threadIdx.x;
  if (idx < NN) g8[idx] = (unsigned char)s2g[n2s[idx]];
}

// ---------------- layer-0 embedding: bf16x8 row copies from ztabh ----------------
__global__ __launch_bounds__(256) void ngnn97_embed(const int* __restrict__ z,
                                                    const unsigned short* __restrict__ ztabh,
                                                    unsigned short* __restrict__ xh) {
  int idx = blockIdx.x * 256 + threadIdx.x;
  int node = idx >> 3, sub = idx & 7;
  if (node < NN) {
    int zz = z[node];
    *(bf16x8*)(xh + (size_t)node * 64 + sub * 8) =
        *(const bf16x8*)(ztabh + zz * 64 + sub * 8);
  }
}

// ---------------- neighbor aggregation: 8 nodes/wave, 2-way edge unroll ----------------
__global__ __launch_bounds__(256) void ngnn97_agg(const unsigned short* __restrict__ xh,
                                                  const int* __restrict__ rowp,
                                                  const int* __restrict__ srcs,
                                                  unsigned short* __restrict__ aggx) {
  int t = threadIdx.x;
  int wv = t >> 6, lane = t & 63;
  int grp = lane >> 3, sub = lane & 7;
  int node = blockIdx.x * 32 + wv * 8 + grp;
  if (node >= NN) return;
  int b = rowp[node], e = rowp[node + 1];
  float acc[8];
#pragma unroll
  for (int i = 0; i < 8; i++) acc[i] = 0.f;
  int p = b;
  for (; p + 2 <= e; p += 2) {
    int s0 = srcs[p], s1 = srcs[p + 1];
    bf16x8 v0 = *(const bf16x8*)(xh + (size_t)s0 * 64 + sub * 8);
    bf16x8 v1 = *(const bf16x8*)(xh + (size_t)s1 * 64 + sub * 8);
#pragma unroll
    for (int i = 0; i < 8; i++)
      acc[i] += ngnn97_bf2f((unsigned short)v0[i]) + ngnn97_bf2f((unsigned short)v1[i]);
  }
  if (p < e) {
    int s0 = srcs[p];
    bf16x8 v0 = *(const bf16x8*)(xh + (size_t)s0 * 64 + sub * 8);
#pragma unroll
    for (int i = 0; i < 8; i++) acc[i] += ngnn97_bf2f((unsigned short)v0[i]);
  }
  bf16x8 ov;
#pragma unroll
  for (int i = 0; i < 8; i++) ov[i] = (short)ngnn97_f2bf(acc[i]);
  *(bf16x8*)(aggx + (size_t)node * 64 + sub * 8) = ov;
}

// ---------------- GRU via MFMA (+ optional next-layer transform) ----------------
// Block = 128 nodes, 4 waves; wave w owns strip [nbase+32w, +32) -> ZERO barriers.
// __launch_bounds__(256,4): allow 128 VGPRs so the compiler can pipeline B-loads.
__global__ __launch_bounds__(256, 4) void ngnn97_gru(
    unsigned short* __restrict__ xh, const unsigned short* __restrict__ aggx,
    const unsigned short* __restrict__ Ubt, const float* __restrict__ Ub,
    const unsigned short* __restrict__ Vbt, const float* __restrict__ tfb,
    const int* __restrict__ z, const unsigned short* __restrict__ ztabh,
    int do_transform) {
  __shared__ unsigned short Abuf[128 * 72];    // xh strip staging + xn scratch, 18.4 KB
  const int t = threadIdx.x;
  const int lane = t & 63, w = t >> 6;
  const int ncol = lane & 15, quad = lane >> 4;
  const int nbase = blockIdx.x * 128;
  const int strip = 32 * w;

  // ---- stage xh strip rows -> Abuf cols 0..63 (strip-local) ----
#pragma unroll
  for (int i = 0; i < 8; i++) {
    int chunk = i * 64 + lane;                 // 512 = 32 rows x 16 ushort4
    int r2 = chunk >> 4, c4 = (chunk & 15) << 2;
    int node = nbase + strip + r2;
    ushort4 qx = make_ushort4(0, 0, 0, 0);
    if (node < NN) qx = *(const ushort4*)(xh + (size_t)node * 64 + c4);
    *(ushort4*)(Abuf + (strip + r2) * 72 + c4) = qx;
  }

  // ---- A-frags: aggx half direct-global, xh half from LDS ----
  bf16x8 afrA[2][2], afrX[2][2];
#pragma unroll
  for (int mm = 0; mm < 2; mm++) {
    int node = nbase + strip + mm * 16 + ncol;
#pragma unroll
    for (int kc = 0; kc < 2; kc++) {
      bf16x8 va = (bf16x8){0, 0, 0, 0, 0, 0, 0, 0};
      if (node < NN) va = *(const bf16x8*)(aggx + (size_t)node * 64 + quad * 8 + kc * 32);
      afrA[mm][kc] = va;
      afrX[mm][kc] = *(const bf16x8*)(Abuf + (strip + mm * 16 + ncol) * 72 + quad * 8 + kc * 32);
    }
  }

  // ---- gate GEMM + GRU update; xn overwrites Abuf cols 0..63 ----
#pragma unroll
  for (int c = 0; c < 4; c++) {
    f32x4 aR[2], aZ[2], aN[2], aH[2];
#pragma unroll
    for (int mm = 0; mm < 2; mm++) {
      aR[mm] = (f32x4){0.f, 0.f, 0.f, 0.f}; aZ[mm] = aR[mm];
      aN[mm] = aR[mm]; aH[mm] = aR[mm];
    }
#pragma unroll
    for (int kc = 0; kc < 4; kc++) {
      const unsigned short* ub = Ubt + (size_t)(c * 16 + ncol) * 128 + quad * 8 + kc * 32;
      bf16x8 bR = *(const bf16x8*)(ub);
      bf16x8 bZ = *(const bf16x8*)(ub + 64 * 128);
      bf16x8 bX = (kc < 2) ? *(const bf16x8*)(ub + 128 * 128)
                           : *(const bf16x8*)(ub + 192 * 128);
#pragma unroll
      for (int mm = 0; mm < 2; mm++) {
        bf16x8 a = (kc < 2) ? afrA[mm][kc] : afrX[mm][kc - 2];
        aR[mm] = __builtin_amdgcn_mfma_f32_16x16x32_bf16(a, bR, aR[mm], 0, 0, 0);
        aZ[mm] = __builtin_amdgcn_mfma_f32_16x16x32_bf16(a, bZ, aZ[mm], 0, 0, 0);
        if (kc < 2) aN[mm] = __builtin_amdgcn_mfma_f32_16x16x32_bf16(a, bX, aN[mm], 0, 0, 0);
        else        aH[mm] = __builtin_amdgcn_mfma_f32_16x16x32_bf16(a, bX, aH[mm], 0, 0, 0);
      }
    }
    int j = c * 16 + ncol;
    float bRs = Ub[j], bZs = Ub[64 + j], bNs = Ub[128 + j], bHs = Ub[192 + j];
#pragma unroll
    for (int mm = 0; mm < 2; mm++)
#pragma unroll
      for (int r = 0; r < 4; r++) {
        int row = strip + mm * 16 + quad * 4 + r;
        float R = aR[mm][r] + bRs, Z = aZ[mm][r] + bZs;
        float Nv = aN[mm][r] + bNs, H = aH[mm][r] + bHs;
        float rg = 1.f / (1.f + __expf(-R));
        float ug = 1.f / (1.f + __expf(-Z));
        float e2 = __expf(2.f * (Nv + rg * H));
        float nn2 = 1.f - 2.f / (e2 + 1.f);    // tanh via fast exp (saturates safely)
        float xo = ngnn97_bf2f(Abuf[row * 72 + j]);
        Abuf[row * 72 + j] = ngnn97_f2bf((1.f - ug) * nn2 + ug * xo);
      }
  }

  if (do_transform) {
    // ---- A2-frags: xn from LDS, ze direct from bf16 ztab ----
    bf16x8 afrN[2][2], afrE[2][2];
#pragma unroll
    for (int mm = 0; mm < 2; mm++) {
      int node = nbase + strip + mm * 16 + ncol;
      int zz = (node < NN) ? z[node] : 0;
#pragma unroll
      for (int kc = 0; kc < 2; kc++) {
        afrN[mm][kc] = *(const bf16x8*)(Abuf + (strip + mm * 16 + ncol) * 72 + quad * 8 + kc * 32);
        afrE[mm][kc] = *(const bf16x8*)(ztabh + zz * 64 + quad * 8 + kc * 32);
      }
    }
    // ---- transform GEMM -> Abuf cols 0..63 ----
#pragma unroll
    for (int c2 = 0; c2 < 4; c2++) {
      f32x4 acc[2];
      acc[0] = (f32x4){0.f, 0.f, 0.f, 0.f}; acc[1] = acc[0];
#pragma unroll
      for (int kc = 0; kc < 4; kc++) {
        bf16x8 bV = *(const bf16x8*)(Vbt + (size_t)(c2 * 16 + ncol) * 128 + quad * 8 + kc * 32);
#pragma unroll
        for (int mm = 0; mm < 2; mm++) {
          bf16x8 a = (kc < 2) ? afrN[mm][kc] : afrE[mm][kc - 2];
          acc[mm] = __builtin_amdgcn_mfma_f32_16x16x32_bf16(a, bV, acc[mm], 0, 0, 0);
        }
      }
      int j = c2 * 16 + ncol;
      float bt = tfb[j];
#pragma unroll
      for (int mm = 0; mm < 2; mm++)
#pragma unroll
        for (int r = 0; r < 4; r++) {
          int row = strip + mm * 16 + quad * 4 + r;
          Abuf[row * 72 + j] = ngnn97_f2bf(acc[mm][r] + bt);
        }
    }
  }

  // ---- coalesced store: Abuf cols 0..63 (strip) -> xh ----
#pragma unroll
  for (int i = 0; i < 8; i++) {
    int chunk = i * 64 + lane;
    int r2 = chunk >> 4, c4 = (chunk & 15) << 2;
    int node = nbase + strip + r2;
    if (node < NN)
      *(ushort4*)(xh + (size_t)node * 64 + c4) = *(const ushort4*)(Abuf + (strip + r2) * 72 + c4);
  }
}

// ---------------- pooling: 2048 blocks x 245 nodes, private slots, plain-store flush ----------------
__global__ __launch_bounds__(256) void ngnn97_pool(const unsigned short* __restrict__ xh,
                                                   const unsigned char* __restrict__ g8,
                                                   float* __restrict__ gpart) {
  __shared__ float gacc[4096];
  int t = threadIdx.x;
  int wv = t >> 6, lane = t & 63;
  int grp = lane >> 3, sub = lane & 7;
  int chain = wv * 8 + grp;                  // 0..31
  for (int i = t; i < 4096; i += 256) gacc[i] = 0.f;
  __syncthreads();
  int base = blockIdx.x * PNPB;
#pragma unroll
  for (int it = 0; it < 8; it++) {
    int idx = it * 32 + chain;
    if (idx < PNPB) {
      int node = base + idx;
      if (node < NN) {
        int g = g8[node];
        bf16x8 v = *(const bf16x8*)(xh + (size_t)node * 64 + sub * 8);
#pragma unroll
        for (int i = 0; i < 8; i++) {
          int k2 = (i + grp) & 7;            // bank stagger across groups
          atomicAdd(&gacc[g * 64 + sub * 8 + k2], ngnn97_bf2f((unsigned short)v[k2]));
        }
      }
    }
  }
  __syncthreads();
  float4* slot = (float4*)(gpart + (size_t)blockIdx.x * 4096);
  const float4* src4 = (const float4*)gacc;
  for (int i = t; i < 1024; i += 256) slot[i] = src4[i];
}

// ---------------- reduce stage A: fold 8 slots -> slot 8b (in place, 256 blocks) ----------------
__global__ __launch_bounds__(256) void ngnn97_reda(float* __restrict__ gpart) {
  int b = blockIdx.x;                        // 0..255
  size_t k0 = (size_t)b * 8;
  for (int i = threadIdx.x; i < 4096; i += 256) {
    float s = 0.f;
#pragma unroll
    for (int k = 0; k < 8; k++) s += gpart[(k0 + k) * 4096 + i];
    gpart[k0 * 4096 + i] = s;
  }
}

// ---------------- reduce stage B: fold 256 slots (stride 8) -> gpool ----------------
__global__ __launch_bounds__(256) void ngnn97_redb(const float* __restrict__ gpart,
                                                   float* __restrict__ gpool) {
  int i = blockIdx.x * 256 + threadIdx.x;    // 0..4095
  float s = 0.f;
#pragma unroll 8
  for (int k = 0; k < 256; k++) s += gpart[(size_t)(k * 8) * 4096 + i];
  gpool[i] = s;
}

// ---------------- MLP head (output: float32 [G,1]) ----------------
__global__ __launch_bounds__(256) void ngnn97_head(
    const float* __restrict__ gpool,
    const float* __restrict__ W1, const float* __restrict__ b1,
    const float* __restrict__ W2, const float* __restrict__ b2,
    const float* __restrict__ W3, const float* __restrict__ b3,
    float* __restrict__ out) {
  __shared__ float gp[4096];
  __shared__ float h1[2048];
  __shared__ float h2[1024];
  int t = threadIdx.x;
  for (int i = t; i < 4096; i += 256) gp[i] = gpool[i];
  __syncthreads();
  for (int i = t; i < 2048; i += 256) {
    int g = i >> 5, o = i & 31;
    float a = b1[o];
    for (int d = 0; d < 64; d++) a = fmaf(gp[g * 64 + d], W1[o * 64 + d], a);
    h1[i] = (a > 0.f) ? a : (__expf(a) - 1.f);
  }
  __syncthreads();
  for (int i = t; i < 1024; i += 256) {
    int g = i >> 4, o = i & 15;
    float a = b2[o];
    for (int d = 0; d < 32; d++) a = fmaf(h1[g * 32 + d], W2[o * 32 + d], a);
    h2[i] = (a > 0.f) ? a : (__expf(a) - 1.f);
  }
  __syncthreads();
  if (t < 64) {
    float a = b3[0];
    for (int d = 0; d < 16; d++) a = fmaf(h2[t * 16 + d], W3[d], a);
    out[t] = a;
  }
}

// ---------------- workspace layout (byte offsets) ----------------
#define OFF_XH    ((size_t)0)                          // N*64 bf16 = 64,000,000
#define OFF_AGG   ((size_t)64000000)                   // N*64 bf16 = 64,000,000
#define OFF_CNT   ((size_t)128000000)                  // NP int
#define OFF_ROW   (OFF_CNT + (size_t)NP * 4)
#define OFF_CUR   (OFF_ROW + (size_t)NP * 4)
#define OFF_SRC   (OFF_CUR + (size_t)NP * 4)           // E int
#define OFF_BSUM  (OFF_SRC + (size_t)EE * 4)
#define OFF_BOFF  (OFF_BSUM + (size_t)2048)
#define OFF_U     (OFF_BOFF + (size_t)2048)            // Ubt bf16 5*256*128
#define OFF_UB    (OFF_U + (size_t)327680)             // Ub f32 5*256
#define OFF_V     (OFF_UB + (size_t)5120)              // Vbt bf16 4*64*128
#define OFF_GP    (OFF_V + (size_t)65536)              // gpool 64*64 f32
#define OFF_G8    (OFF_GP + (size_t)16384)             // N uint8 (padded)
#define OFF_ZTH   (OFF_G8 + (size_t)500736)            // ztabh bf16 5*100*64
#define OFF_GPART (OFF_ZTH + (size_t)64000)            // 2048*4096 f32 = 33.5 MB
#define WS_NEED   (OFF_GPART + (size_t)PBLK * 16384)   // ~= 173.6 MB (proven budget 203.8)

extern "C" void kernel_launch(void* const* d_in, const int* in_sizes, int n_in,
                              void* d_out, int out_size, void* d_ws, size_t ws_size,
                              hipStream_t stream) {
  float* out = (float*)d_out;   // reference output is float32 [G,1]
  if (ws_size < WS_NEED) {
    ngnn97_code<<<1, 64, 0, stream>>>(out, 7.0f);
    return;
  }

  const int* z    = (const int*)d_in[0];
  const int* ei   = (const int*)d_in[1];
  const int* n2s  = (const int*)d_in[2];
  const int* s2g  = (const int*)d_in[3];
  const float* ztab = (const float*)d_in[4];
  const float* tfW  = (const float*)d_in[5];
  const float* tfb  = (const float*)d_in[6];
  const float* ggc  = (const float*)d_in[7];
  const float* wih  = (const float*)d_in[8];
  const float* whh  = (const float*)d_in[9];
  const float* bih  = (const float*)d_in[10];
  const float* bhh  = (const float*)d_in[11];
  const float* W1   = (const float*)d_in[12];
  const float* b1   = (const float*)d_in[13];
  const float* W2   = (const float*)d_in[14];
  const float* b2   = (const float*)d_in[15];
  const float* W3   = (const float*)d_in[16];
  const float* b3   = (const float*)d_in[17];

  char* ws = (char*)d_ws;
  unsigned short* xh     = (unsigned short*)(ws + OFF_XH);
  unsigned short* aggx   = (unsigned short*)(ws + OFF_AGG);
  int*            counts = (int*)(ws + OFF_CNT);
  int*            rowp   = (int*)(ws + OFF_ROW);
  int*            curs   = (int*)(ws + OFF_CUR);
  int*            srcs   = (int*)(ws + OFF_SRC);
  int*            bsum   = (int*)(ws + OFF_BSUM);
  int*            boff   = (int*)(ws + OFF_BOFF);
  unsigned short* Ubt    = (unsigned short*)(ws + OFF_U);
  float*          Ub     = (float*)(ws + OFF_UB);
  unsigned short* Vbt    = (unsigned short*)(ws + OFF_V);
  float*          gpool  = (float*)(ws + OFF_GP);
  unsigned char*  g8     = (unsigned char*)(ws + OFF_G8);
  unsigned short* ztabh  = (unsigned short*)(ws + OFF_ZTH);
  float*          gpart  = (float*)(ws + OFF_GPART);

  hipMemsetAsync(counts, 0, (size_t)NP * 4, stream);

  ngnn97_pre<<<899, 256, 0, stream>>>(ggc, wih, whh, bih, bhh, tfW, ztab, Ubt, Ub, Vbt, ztabh);
  ngnn97_g8<<<(NN + 255) / 256, 256, 0, stream>>>(n2s, s2g, g8);

  // CSR by dst
  const int* srcp = ei;
  const int* dstp = ei + EE;
  ngnn97_hist<<<(EE + 255) / 256, 256, 0, stream>>>(dstp, counts);
  ngnn97_red<<<NBLK, 256, 0, stream>>>(counts, bsum);
  ngnn97_scan1<<<1, 512, 0, stream>>>(bsum, boff);
  ngnn97_scan2<<<NBLK, 256, 0, stream>>>(counts, boff, rowp, curs);
  ngnn97_fill<<<(EE + 255) / 256, 256, 0, stream>>>(srcp, dstp, curs, srcs);
  // rowp[n]..rowp[n+1] now bounds node n's incoming-edge list

  ngnn97_embed<<<(NN * 8 + 255) / 256, 256, 0, stream>>>(z, ztabh, xh);

  for (int l = 0; l < 5; l++) {
    ngnn97_agg<<<(NN + 31) / 32, 256, 0, stream>>>(xh, rowp, srcs, aggx);
    ngnn97_gru<<<(NN + 127) / 128, 256, 0, stream>>>(
        xh, aggx, Ubt + (size_t)l * 32768, Ub + (size_t)l * 256,
        Vbt + (size_t)(l < 4 ? l : 0) * 8192, tfb + (size_t)(l < 4 ? l : 0) * 64,
        z, ztabh + (size_t)(l < 4 ? l + 1 : 0) * 6400, (l < 4) ? 1 : 0);
  }

  ngnn97_pool<<<PBLK, 256, 0, stream>>>(xh, g8, gpart);
  ngnn97_reda<<<256, 256, 0, stream>>>(gpart);
  ngnn97_redb<<<16, 256, 0, stream>>>(gpart, gpool);
  ngnn97_head<<<1, 256, 0, stream>>>(gpool, W1, b1, W2, b2, W3, b3, out);
}

// Round 17
// 1225.012 us; speedup vs baseline: 1.1063x; 1.1063x over previous
//
#include <hip/hip_runtime.h>
#include <hip/hip_bf16.h>

// ---------------- problem constants ----------------
#define NN 500000
#define EE 1250000
#define NP 501760          // padded node count
#define NBLK 489           // scan blocks of 1024
#define GCAP 16384         // nlist capacity per graph (expected 7812, 2.1x margin)

typedef __attribute__((ext_vector_type(8))) short bf16x8;
typedef __attribute__((ext_vector_type(4))) float f32x4;

__device__ __forceinline__ float ngnn97_bf2f(unsigned short u) {
  return __uint_as_float(((unsigned int)u) << 16);
}
__device__ __forceinline__ unsigned short ngnn97_f2bf(float f) {
  union { __hip_bfloat16 b; unsigned short u; } cv;
  cv.b = __float2bfloat16(f);
  return cv.u;
}

// ---------------- diagnostic code writer (guard path only) ----------------
__global__ void ngnn97_code(float* __restrict__ out, float v) {
  if (threadIdx.x < 64) out[threadIdx.x] = v;
}

// ---------------- precompute folded weights (bf16, MFMA-B layout) + bf16 ztab ----------------
__global__ __launch_bounds__(256) void ngnn97_pre(
    const float* __restrict__ ggc, const float* __restrict__ wih,
    const float* __restrict__ whh, const float* __restrict__ bih,
    const float* __restrict__ bhh, const float* __restrict__ tfW,
    const float* __restrict__ ztab,
    unsigned short* __restrict__ Ubt, float* __restrict__ Ub,
    unsigned short* __restrict__ Vbt, unsigned short* __restrict__ ztabh) {
  int idx = blockIdx.x * 256 + threadIdx.x;
  if (idx < 163840) {                      // Ubt: 5*256*128
    int l = idx >> 15, r = idx & 32767;
    int n = r >> 7, k = r & 127;
    float v = 0.f;
    if (k < 64) {
      if (n < 192) {
        const float* gp = ggc + l * 4096 + k * 64;
        const float* wp = wih + l * 12288 + n * 64;
        float acc = 0.f;
#pragma unroll
        for (int t2 = 0; t2 < 64; t2++) acc = fmaf(gp[t2], wp[t2], acc);
        v = acc;
      }
    } else {
      int k2 = k - 64;
      if (n < 128) v = whh[l * 12288 + n * 64 + k2];
      else if (n >= 192) v = whh[l * 12288 + (n - 64) * 64 + k2];
    }
    Ubt[idx] = ngnn97_f2bf(v);
  } else if (idx < 196608) {               // Vbt: 4*64*128 (= tfW flat)
    int i2 = idx - 163840;
    Vbt[i2] = ngnn97_f2bf(tfW[i2]);
  } else if (idx < 197888) {               // Ub: 5*256
    int i2 = idx - 196608;
    int l = i2 >> 8, j = i2 & 255;
    float v;
    if (j < 128)      v = bih[l * 192 + j] + bhh[l * 192 + j];
    else if (j < 192) v = bih[l * 192 + j];
    else              v = bhh[l * 192 + j - 64];
    Ub[i2] = v;
  } else if (idx < 229888) {               // ztabh: 5*100*64 bf16
    int i2 = idx - 197888;
    ztabh[i2] = ngnn97_f2bf(ztab[i2]);
  }
}

// ---------------- CSR build ----------------
__global__ __launch_bounds__(256) void ngnn97_hist(const int* __restrict__ dst, int* __restrict__ counts) {
  int e = blockIdx.x * 256 + threadIdx.x;
  if (e < EE) atomicAdd(&counts[dst[e]], 1);
}

__global__ __launch_bounds__(256) void ngnn97_red(const int* __restrict__ counts, int* __restrict__ bsum) {
  __shared__ int s[256];
  int t = threadIdx.x, base = blockIdx.x * 1024;
  int v = 0;
#pragma unroll
  for (int i = 0; i < 4; i++) v += counts[base + t + i * 256];
  s[t] = v; __syncthreads();
  for (int o = 128; o > 0; o >>= 1) { if (t < o) s[t] += s[t + o]; __syncthreads(); }
  if (t == 0) bsum[blockIdx.x] = s[0];
}

__global__ __launch_bounds__(512) void ngnn97_scan1(const int* __restrict__ bsum, int* __restrict__ boff) {
  __shared__ int s[512];
  int t = threadIdx.x;
  int v = (t < NBLK) ? bsum[t] : 0;
  s[t] = v; __syncthreads();
  for (int o = 1; o < 512; o <<= 1) {
    int a = (t >= o) ? s[t - o] : 0;
    __syncthreads(); s[t] += a; __syncthreads();
  }
  if (t < NBLK) boff[t] = s[t] - v;   // exclusive
}

__global__ __launch_bounds__(256) void ngnn97_scan2(const int* __restrict__ counts, const int* __restrict__ boff,
                                                    int* __restrict__ row_ptr, int* __restrict__ cursor) {
  __shared__ int s[256];
  int t = threadIdx.x, base = blockIdx.x * 1024;
  int4 c = *(const int4*)(counts + base + t * 4);
  int tsum = c.x + c.y + c.z + c.w;
  s[t] = tsum; __syncthreads();
  for (int o = 1; o < 256; o <<= 1) {
    int a = (t >= o) ? s[t - o] : 0;
    __syncthreads(); s[t] += a; __syncthreads();
  }
  int off = boff[blockIdx.x] + s[t] - tsum;
  int4 r;
  r.x = off; r.y = off + c.x; r.z = off + c.x + c.y; r.w = off + c.x + c.y + c.z;
  *(int4*)(row_ptr + base + t * 4) = r;
  *(int4*)(cursor + base + t * 4) = r;
}

__global__ __launch_bounds__(256) void ngnn97_fill(const int* __restrict__ src, const int* __restrict__ dst,
                                                   int* __restrict__ cursor, int* __restrict__ srcs) {
  int e = blockIdx.x * 256 + threadIdx.x;
  if (e < EE) {
    int pos = atomicAdd(&cursor[dst[e]], 1);
    srcs[pos] = src[e];
  }
}

// ---------------- node -> graph id precompute (uint8) ----------------
__global__ __launch_bounds__(256) void ngnn97_g8(const int* __restrict__ n2s, const int* __restrict__ s2g,
                                                 unsigned char* __restrict__ g8) {
  int idx = blockIdx.x * 256 + threadIdx.x;
  if (idx < NN) g8[idx] = (unsigned char)s2g[n2s[idx]];
}

// ---------------- bucket nodes by graph: LDS hist + two-pass fill ----------------
// nlist[g*GCAP + i] = node ids of graph g; gcur[g] ends as count per graph.
__global__ __launch_bounds__(256) void ngnn97_bucket(const unsigned char* __restrict__ g8,
                                                     int* __restrict__ gcur, int* __restrict__ nlist) {
  __shared__ int hcnt[64];
  __shared__ int hbase[64];
  int t = threadIdx.x;
  int base = blockIdx.x * 1024;
  if (t < 64) hcnt[t] = 0;
  __syncthreads();
#pragma unroll
  for (int i = 0; i < 4; i++) {
    int node = base + i * 256 + t;
    if (node < NN) atomicAdd(&hcnt[g8[node]], 1);
  }
  __syncthreads();
  if (t < 64) {
    int c = hcnt[t];
    hbase[t] = (c > 0) ? atomicAdd(&gcur[t], c) : 0;
    hcnt[t] = 0;
  }
  __syncthreads();
#pragma unroll
  for (int i = 0; i < 4; i++) {
    int node = base + i * 256 + t;
    if (node < NN) {
      int g = g8[node];
      int loc = atomicAdd(&hcnt[g], 1);
      int pos = hbase[g] + loc;
      if (pos < GCAP) nlist[g * GCAP + pos] = node;
    }
  }
}

// ---------------- layer-0 embedding: bf16x8 row copies from ztabh ----------------
__global__ __launch_bounds__(256) void ngnn97_embed(const int* __restrict__ z,
                                                    const unsigned short* __restrict__ ztabh,
                                                    unsigned short* __restrict__ xh) {
  int idx = blockIdx.x * 256 + threadIdx.x;
  int node = idx >> 3, sub = idx & 7;
  if (node < NN) {
    int zz = z[node];
    *(bf16x8*)(xh + (size_t)node * 64 + sub * 8) =
        *(const bf16x8*)(ztabh + zz * 64 + sub * 8);
  }
}

// ---------------- neighbor aggregation: 8 nodes/wave, 2-way edge unroll ----------------
__global__ __launch_bounds__(256) void ngnn97_agg(const unsigned short* __restrict__ xh,
                                                  const int* __restrict__ rowp,
                                                  const int* __restrict__ srcs,
                                                  unsigned short* __restrict__ aggx) {
  int t = threadIdx.x;
  int wv = t >> 6, lane = t & 63;
  int grp = lane >> 3, sub = lane & 7;
  int node = blockIdx.x * 32 + wv * 8 + grp;
  if (node >= NN) return;
  int b = rowp[node], e = rowp[node + 1];
  float acc[8];
#pragma unroll
  for (int i = 0; i < 8; i++) acc[i] = 0.f;
  int p = b;
  for (; p + 2 <= e; p += 2) {
    int s0 = srcs[p], s1 = srcs[p + 1];
    bf16x8 v0 = *(const bf16x8*)(xh + (size_t)s0 * 64 + sub * 8);
    bf16x8 v1 = *(const bf16x8*)(xh + (size_t)s1 * 64 + sub * 8);
#pragma unroll
    for (int i = 0; i < 8; i++)
      acc[i] += ngnn97_bf2f((unsigned short)v0[i]) + ngnn97_bf2f((unsigned short)v1[i]);
  }
  if (p < e) {
    int s0 = srcs[p];
    bf16x8 v0 = *(const bf16x8*)(xh + (size_t)s0 * 64 + sub * 8);
#pragma unroll
    for (int i = 0; i < 8; i++) acc[i] += ngnn97_bf2f((unsigned short)v0[i]);
  }
  bf16x8 ov;
#pragma unroll
  for (int i = 0; i < 8; i++) ov[i] = (short)ngnn97_f2bf(acc[i]);
  *(bf16x8*)(aggx + (size_t)node * 64 + sub * 8) = ov;
}

// ---------------- GRU via MFMA (+ optional next-layer transform) ----------------
// Block = 128 nodes, 4 waves; wave w owns strip [nbase+32w, +32) -> ZERO barriers.
__global__ __launch_bounds__(256, 4) void ngnn97_gru(
    unsigned short* __restrict__ xh, const unsigned short* __restrict__ aggx,
    const unsigned short* __restrict__ Ubt, const float* __restrict__ Ub,
    const unsigned short* __restrict__ Vbt, const float* __restrict__ tfb,
    const int* __restrict__ z, const unsigned short* __restrict__ ztabh,
    int do_transform) {
  __shared__ unsigned short Abuf[128 * 72];    // xh strip staging + xn scratch, 18.4 KB
  const int t = threadIdx.x;
  const int lane = t & 63, w = t >> 6;
  const int ncol = lane & 15, quad = lane >> 4;
  const int nbase = blockIdx.x * 128;
  const int strip = 32 * w;

  // ---- stage xh strip rows -> Abuf cols 0..63 (strip-local) ----
#pragma unroll
  for (int i = 0; i < 8; i++) {
    int chunk = i * 64 + lane;                 // 512 = 32 rows x 16 ushort4
    int r2 = chunk >> 4, c4 = (chunk & 15) << 2;
    int node = nbase + strip + r2;
    ushort4 qx = make_ushort4(0, 0, 0, 0);
    if (node < NN) qx = *(const ushort4*)(xh + (size_t)node * 64 + c4);
    *(ushort4*)(Abuf + (strip + r2) * 72 + c4) = qx;
  }

  // ---- A-frags: aggx half direct-global, xh half from LDS ----
  bf16x8 afrA[2][2], afrX[2][2];
#pragma unroll
  for (int mm = 0; mm < 2; mm++) {
    int node = nbase + strip + mm * 16 + ncol;
#pragma unroll
    for (int kc = 0; kc < 2; kc++) {
      bf16x8 va = (bf16x8){0, 0, 0, 0, 0, 0, 0, 0};
      if (node < NN) va = *(const bf16x8*)(aggx + (size_t)node * 64 + quad * 8 + kc * 32);
      afrA[mm][kc] = va;
      afrX[mm][kc] = *(const bf16x8*)(Abuf + (strip + mm * 16 + ncol) * 72 + quad * 8 + kc * 32);
    }
  }

  // ---- gate GEMM + GRU update; xn overwrites Abuf cols 0..63 ----
#pragma unroll
  for (int c = 0; c < 4; c++) {
    f32x4 aR[2], aZ[2], aN[2], aH[2];
#pragma unroll
    for (int mm = 0; mm < 2; mm++) {
      aR[mm] = (f32x4){0.f, 0.f, 0.f, 0.f}; aZ[mm] = aR[mm];
      aN[mm] = aR[mm]; aH[mm] = aR[mm];
    }
#pragma unroll
    for (int kc = 0; kc < 4; kc++) {
      const unsigned short* ub = Ubt + (size_t)(c * 16 + ncol) * 128 + quad * 8 + kc * 32;
      bf16x8 bR = *(const bf16x8*)(ub);
      bf16x8 bZ = *(const bf16x8*)(ub + 64 * 128);
      bf16x8 bX = (kc < 2) ? *(const bf16x8*)(ub + 128 * 128)
                           : *(const bf16x8*)(ub + 192 * 128);
#pragma unroll
      for (int mm = 0; mm < 2; mm++) {
        bf16x8 a = (kc < 2) ? afrA[mm][kc] : afrX[mm][kc - 2];
        aR[mm] = __builtin_amdgcn_mfma_f32_16x16x32_bf16(a, bR, aR[mm], 0, 0, 0);
        aZ[mm] = __builtin_amdgcn_mfma_f32_16x16x32_bf16(a, bZ, aZ[mm], 0, 0, 0);
        if (kc < 2) aN[mm] = __builtin_amdgcn_mfma_f32_16x16x32_bf16(a, bX, aN[mm], 0, 0, 0);
        else        aH[mm] = __builtin_amdgcn_mfma_f32_16x16x32_bf16(a, bX, aH[mm], 0, 0, 0);
      }
    }
    int j = c * 16 + ncol;
    float bRs = Ub[j], bZs = Ub[64 + j], bNs = Ub[128 + j], bHs = Ub[192 + j];
#pragma unroll
    for (int mm = 0; mm < 2; mm++)
#pragma unroll
      for (int r = 0; r < 4; r++) {
        int row = strip + mm * 16 + quad * 4 + r;
        float R = aR[mm][r] + bRs, Z = aZ[mm][r] + bZs;
        float Nv = aN[mm][r] + bNs, H = aH[mm][r] + bHs;
        float rg = 1.f / (1.f + __expf(-R));
        float ug = 1.f / (1.f + __expf(-Z));
        float e2 = __expf(2.f * (Nv + rg * H));
        float nn2 = 1.f - 2.f / (e2 + 1.f);    // tanh via fast exp (saturates safely)
        float xo = ngnn97_bf2f(Abuf[row * 72 + j]);
        Abuf[row * 72 + j] = ngnn97_f2bf((1.f - ug) * nn2 + ug * xo);
      }
  }

  if (do_transform) {
    // ---- A2-frags: xn from LDS, ze direct from bf16 ztab ----
    bf16x8 afrN[2][2], afrE[2][2];
#pragma unroll
    for (int mm = 0; mm < 2; mm++) {
      int node = nbase + strip + mm * 16 + ncol;
      int zz = (node < NN) ? z[node] : 0;
#pragma unroll
      for (int kc = 0; kc < 2; kc++) {
        afrN[mm][kc] = *(const bf16x8*)(Abuf + (strip + mm * 16 + ncol) * 72 + quad * 8 + kc * 32);
        afrE[mm][kc] = *(const bf16x8*)(ztabh + zz * 64 + quad * 8 + kc * 32);
      }
    }
    // ---- transform GEMM -> Abuf cols 0..63 ----
#pragma unroll
    for (int c2 = 0; c2 < 4; c2++) {
      f32x4 acc[2];
      acc[0] = (f32x4){0.f, 0.f, 0.f, 0.f}; acc[1] = acc[0];
#pragma unroll
      for (int kc = 0; kc < 4; kc++) {
        bf16x8 bV = *(const bf16x8*)(Vbt + (size_t)(c2 * 16 + ncol) * 128 + quad * 8 + kc * 32);
#pragma unroll
        for (int mm = 0; mm < 2; mm++) {
          bf16x8 a = (kc < 2) ? afrN[mm][kc] : afrE[mm][kc - 2];
          acc[mm] = __builtin_amdgcn_mfma_f32_16x16x32_bf16(a, bV, acc[mm], 0, 0, 0);
        }
      }
      int j = c2 * 16 + ncol;
      float bt = tfb[j];
#pragma unroll
      for (int mm = 0; mm < 2; mm++)
#pragma unroll
        for (int r = 0; r < 4; r++) {
          int row = strip + mm * 16 + quad * 4 + r;
          Abuf[row * 72 + j] = ngnn97_f2bf(acc[mm][r] + bt);
        }
    }
  }

  // ---- coalesced store: Abuf cols 0..63 (strip) -> xh ----
#pragma unroll
  for (int i = 0; i < 8; i++) {
    int chunk = i * 64 + lane;
    int r2 = chunk >> 4, c4 = (chunk & 15) << 2;
    int node = nbase + strip + r2;
    if (node < NN)
      *(ushort4*)(xh + (size_t)node * 64 + c4) = *(const ushort4*)(Abuf + (strip + r2) * 72 + c4);
  }
}

// ---------------- pooling: bucketed contiguous reduction, zero hot-loop atomics ----------------
// Block (g = bid>>4, chunk = bid&15): sums rows nlist[g][r0..r1) with register accums.
__global__ __launch_bounds__(256) void ngnn97_pool(const unsigned short* __restrict__ xh,
                                                   const int* __restrict__ nlist,
                                                   const int* __restrict__ gcur,
                                                   float* __restrict__ gpool) {
  __shared__ float part[4][64];
  int t = threadIdx.x;
  int lane = t & 63, wv = t >> 6;
  int g = blockIdx.x >> 4, c = blockIdx.x & 15;
  int cnt = gcur[g];
  if (cnt > GCAP) cnt = GCAP;
  int r0 = (c * cnt) >> 4, r1 = ((c + 1) * cnt) >> 4;
  const int* nl = nlist + g * GCAP;
  float a0 = 0.f, a1 = 0.f;
  int r = r0 + wv;
  for (; r + 4 < r1; r += 8) {
    int n0 = nl[r], n1 = nl[r + 4];
    a0 += ngnn97_bf2f(xh[(size_t)n0 * 64 + lane]);
    a1 += ngnn97_bf2f(xh[(size_t)n1 * 64 + lane]);
  }
  if (r < r1) a0 += ngnn97_bf2f(xh[(size_t)nl[r] * 64 + lane]);
  part[wv][lane] = a0 + a1;
  __syncthreads();
  if (t < 64)
    atomicAdd(&gpool[g * 64 + t], part[0][t] + part[1][t] + part[2][t] + part[3][t]);
}

// ---------------- MLP head (output: float32 [G,1]) ----------------
__global__ __launch_bounds__(256) void ngnn97_head(
    const float* __restrict__ gpool,
    const float* __restrict__ W1, const float* __restrict__ b1,
    const float* __restrict__ W2, const float* __restrict__ b2,
    const float* __restrict__ W3, const float* __restrict__ b3,
    float* __restrict__ out) {
  __shared__ float gp[4096];
  __shared__ float h1[2048];
  __shared__ float h2[1024];
  int t = threadIdx.x;
  for (int i = t; i < 4096; i += 256) gp[i] = gpool[i];
  __syncthreads();
  for (int i = t; i < 2048; i += 256) {
    int g = i >> 5, o = i & 31;
    float a = b1[o];
    for (int d = 0; d < 64; d++) a = fmaf(gp[g * 64 + d], W1[o * 64 + d], a);
    h1[i] = (a > 0.f) ? a : (__expf(a) - 1.f);
  }
  __syncthreads();
  for (int i = t; i < 1024; i += 256) {
    int g = i >> 4, o = i & 15;
    float a = b2[o];
    for (int d = 0; d < 32; d++) a = fmaf(h1[g * 32 + d], W2[o * 32 + d], a);
    h2[i] = (a > 0.f) ? a : (__expf(a) - 1.f);
  }
  __syncthreads();
  if (t < 64) {
    float a = b3[0];
    for (int d = 0; d < 16; d++) a = fmaf(h2[t * 16 + d], W3[d], a);
    out[t] = a;
  }
}

// ---------------- workspace layout (byte offsets) ----------------
#define OFF_XH    ((size_t)0)                          // N*64 bf16 = 64,000,000
#define OFF_AGG   ((size_t)64000000)                   // N*64 bf16 = 64,000,000
#define OFF_CNT   ((size_t)128000000)                  // NP int
#define OFF_ROW   (OFF_CNT + (size_t)NP * 4)
#define OFF_CUR   (OFF_ROW + (size_t)NP * 4)
#define OFF_SRC   (OFF_CUR + (size_t)NP * 4)           // E int
#define OFF_BSUM  (OFF_SRC + (size_t)EE * 4)
#define OFF_BOFF  (OFF_BSUM + (size_t)2048)
#define OFF_U     (OFF_BOFF + (size_t)2048)            // Ubt bf16 5*256*128
#define OFF_UB    (OFF_U + (size_t)327680)             // Ub f32 5*256
#define OFF_V     (OFF_UB + (size_t)5120)              // Vbt bf16 4*64*128
#define OFF_GP    (OFF_V + (size_t)65536)              // gpool 64*64 f32
#define OFF_G8    (OFF_GP + (size_t)16384)             // N uint8 (padded)
#define OFF_ZTH   (OFF_G8 + (size_t)500736)            // ztabh bf16 5*100*64
#define OFF_GCUR  (OFF_ZTH + (size_t)64000)            // 64 ints (+pad)
#define OFF_NL    (OFF_GCUR + (size_t)1024)            // nlist 64*GCAP ints = 4 MB
#define WS_NEED   (OFF_NL + (size_t)64 * GCAP * 4)     // ~= 144.2 MB (proven budget 203.8)

extern "C" void kernel_launch(void* const* d_in, const int* in_sizes, int n_in,
                              void* d_out, int out_size, void* d_ws, size_t ws_size,
                              hipStream_t stream) {
  float* out = (float*)d_out;   // reference output is float32 [G,1]
  if (ws_size < WS_NEED) {
    ngnn97_code<<<1, 64, 0, stream>>>(out, 7.0f);
    return;
  }

  const int* z    = (const int*)d_in[0];
  const int* ei   = (const int*)d_in[1];
  const int* n2s  = (const int*)d_in[2];
  const int* s2g  = (const int*)d_in[3];
  const float* ztab = (const float*)d_in[4];
  const float* tfW  = (const float*)d_in[5];
  const float* tfb  = (const float*)d_in[6];
  const float* ggc  = (const float*)d_in[7];
  const float* wih  = (const float*)d_in[8];
  const float* whh  = (const float*)d_in[9];
  const float* bih  = (const float*)d_in[10];
  const float* bhh  = (const float*)d_in[11];
  const float* W1   = (const float*)d_in[12];
  const float* b1   = (const float*)d_in[13];
  const float* W2   = (const float*)d_in[14];
  const float* b2   = (const float*)d_in[15];
  const float* W3   = (const float*)d_in[16];
  const float* b3   = (const float*)d_in[17];

  char* ws = (char*)d_ws;
  unsigned short* xh     = (unsigned short*)(ws + OFF_XH);
  unsigned short* aggx   = (unsigned short*)(ws + OFF_AGG);
  int*            counts = (int*)(ws + OFF_CNT);
  int*            rowp   = (int*)(ws + OFF_ROW);
  int*            curs   = (int*)(ws + OFF_CUR);
  int*            srcs   = (int*)(ws + OFF_SRC);
  int*            bsum   = (int*)(ws + OFF_BSUM);
  int*            boff   = (int*)(ws + OFF_BOFF);
  unsigned short* Ubt    = (unsigned short*)(ws + OFF_U);
  float*          Ub     = (float*)(ws + OFF_UB);
  unsigned short* Vbt    = (unsigned short*)(ws + OFF_V);
  float*          gpool  = (float*)(ws + OFF_GP);
  unsigned char*  g8     = (unsigned char*)(ws + OFF_G8);
  unsigned short* ztabh  = (unsigned short*)(ws + OFF_ZTH);
  int*            gcur   = (int*)(ws + OFF_GCUR);
  int*            nlist  = (int*)(ws + OFF_NL);

  hipMemsetAsync(counts, 0, (size_t)NP * 4, stream);
  hipMemsetAsync(gpool, 0, 16384, stream);
  hipMemsetAsync(gcur, 0, 1024, stream);

  ngnn97_pre<<<899, 256, 0, stream>>>(ggc, wih, whh, bih, bhh, tfW, ztab, Ubt, Ub, Vbt, ztabh);
  ngnn97_g8<<<(NN + 255) / 256, 256, 0, stream>>>(n2s, s2g, g8);
  ngnn97_bucket<<<NBLK, 256, 0, stream>>>(g8, gcur, nlist);

  // CSR by dst
  const int* srcp = ei;
  const int* dstp = ei + EE;
  ngnn97_hist<<<(EE + 255) / 256, 256, 0, stream>>>(dstp, counts);
  ngnn97_red<<<NBLK, 256, 0, stream>>>(counts, bsum);
  ngnn97_scan1<<<1, 512, 0, stream>>>(bsum, boff);
  ngnn97_scan2<<<NBLK, 256, 0, stream>>>(counts, boff, rowp, curs);
  ngnn97_fill<<<(EE + 255) / 256, 256, 0, stream>>>(srcp, dstp, curs, srcs);
  // rowp[n]..rowp[n+1] now bounds node n's incoming-edge list

  ngnn97_embed<<<(NN * 8 + 255) / 256, 256, 0, stream>>>(z, ztabh, xh);

  for (int l = 0; l < 5; l++) {
    ngnn97_agg<<<(NN + 31) / 32, 256, 0, stream>>>(xh, rowp, srcs, aggx);
    ngnn97_gru<<<(NN + 127) / 128, 256, 0, stream>>>(
        xh, aggx, Ubt + (size_t)l * 32768, Ub + (size_t)l * 256,
        Vbt + (size_t)(l < 4 ? l : 0) * 8192, tfb + (size_t)(l < 4 ? l : 0) * 64,
        z, ztabh + (size_t)(l < 4 ? l + 1 : 0) * 6400, (l < 4) ? 1 : 0);
  }

  ngnn97_pool<<<1024, 256, 0, stream>>>(xh, nlist, gcur, gpool);
  ngnn97_head<<<1, 256, 0, stream>>>(gpool, W1, b1, W2, b2, W3, b3, out);
}

// Round 18
// 1163.781 us; speedup vs baseline: 1.1645x; 1.0526x over previous
//
#include <hip/hip_runtime.h>
#include <hip/hip_bf16.h>

// ---------------- problem constants ----------------
#define NN 500000
#define EE 1250000
#define NP 501760          // padded node count
#define NBLK 489           // scan blocks of 1024
#define GCAP 16384         // nlist capacity per graph (expected 7812, 2.1x margin)

typedef __attribute__((ext_vector_type(8))) short bf16x8;
typedef __attribute__((ext_vector_type(4))) float f32x4;

__device__ __forceinline__ float ngnn97_bf2f(unsigned short u) {
  return __uint_as_float(((unsigned int)u) << 16);
}
__device__ __forceinline__ unsigned short ngnn97_f2bf(float f) {
  union { __hip_bfloat16 b; unsigned short u; } cv;
  cv.b = __float2bfloat16(f);
  return cv.u;
}

// ---------------- diagnostic code writer (guard path only) ----------------
__global__ void ngnn97_code(float* __restrict__ out, float v) {
  if (threadIdx.x < 64) out[threadIdx.x] = v;
}

// ---------------- precompute folded weights (bf16, MFMA-B layout) + bf16 ztab ----------------
__global__ __launch_bounds__(256) void ngnn97_pre(
    const float* __restrict__ ggc, const float* __restrict__ wih,
    const float* __restrict__ whh, const float* __restrict__ bih,
    const float* __restrict__ bhh, const float* __restrict__ tfW,
    const float* __restrict__ ztab,
    unsigned short* __restrict__ Ubt, float* __restrict__ Ub,
    unsigned short* __restrict__ Vbt, unsigned short* __restrict__ ztabh) {
  int idx = blockIdx.x * 256 + threadIdx.x;
  if (idx < 163840) {                      // Ubt: 5*256*128
    int l = idx >> 15, r = idx & 32767;
    int n = r >> 7, k = r & 127;
    float v = 0.f;
    if (k < 64) {
      if (n < 192) {
        const float* gp = ggc + l * 4096 + k * 64;
        const float* wp = wih + l * 12288 + n * 64;
        float acc = 0.f;
#pragma unroll
        for (int t2 = 0; t2 < 64; t2++) acc = fmaf(gp[t2], wp[t2], acc);
        v = acc;
      }
    } else {
      int k2 = k - 64;
      if (n < 128) v = whh[l * 12288 + n * 64 + k2];
      else if (n >= 192) v = whh[l * 12288 + (n - 64) * 64 + k2];
    }
    Ubt[idx] = ngnn97_f2bf(v);
  } else if (idx < 196608) {               // Vbt: 4*64*128 (= tfW flat)
    int i2 = idx - 163840;
    Vbt[i2] = ngnn97_f2bf(tfW[i2]);
  } else if (idx < 197888) {               // Ub: 5*256
    int i2 = idx - 196608;
    int l = i2 >> 8, j = i2 & 255;
    float v;
    if (j < 128)      v = bih[l * 192 + j] + bhh[l * 192 + j];
    else if (j < 192) v = bih[l * 192 + j];
    else              v = bhh[l * 192 + j - 64];
    Ub[i2] = v;
  } else if (idx < 229888) {               // ztabh: 5*100*64 bf16
    int i2 = idx - 197888;
    ztabh[i2] = ngnn97_f2bf(ztab[i2]);
  }
}

// ---------------- CSR build ----------------
__global__ __launch_bounds__(256) void ngnn97_hist(const int* __restrict__ dst, int* __restrict__ counts) {
  int e = blockIdx.x * 256 + threadIdx.x;
  if (e < EE) atomicAdd(&counts[dst[e]], 1);
}

__global__ __launch_bounds__(256) void ngnn97_red(const int* __restrict__ counts, int* __restrict__ bsum) {
  __shared__ int s[256];
  int t = threadIdx.x, base = blockIdx.x * 1024;
  int v = 0;
#pragma unroll
  for (int i = 0; i < 4; i++) v += counts[base + t + i * 256];
  s[t] = v; __syncthreads();
  for (int o = 128; o > 0; o >>= 1) { if (t < o) s[t] += s[t + o]; __syncthreads(); }
  if (t == 0) bsum[blockIdx.x] = s[0];
}

__global__ __launch_bounds__(512) void ngnn97_scan1(const int* __restrict__ bsum, int* __restrict__ boff) {
  __shared__ int s[512];
  int t = threadIdx.x;
  int v = (t < NBLK) ? bsum[t] : 0;
  s[t] = v; __syncthreads();
  for (int o = 1; o < 512; o <<= 1) {
    int a = (t >= o) ? s[t - o] : 0;
    __syncthreads(); s[t] += a; __syncthreads();
  }
  if (t < NBLK) boff[t] = s[t] - v;   // exclusive
}

__global__ __launch_bounds__(256) void ngnn97_scan2(const int* __restrict__ counts, const int* __restrict__ boff,
                                                    int* __restrict__ row_ptr, int* __restrict__ cursor) {
  __shared__ int s[256];
  int t = threadIdx.x, base = blockIdx.x * 1024;
  int4 c = *(const int4*)(counts + base + t * 4);
  int tsum = c.x + c.y + c.z + c.w;
  s[t] = tsum; __syncthreads();
  for (int o = 1; o < 256; o <<= 1) {
    int a = (t >= o) ? s[t - o] : 0;
    __syncthreads(); s[t] += a; __syncthreads();
  }
  int off = boff[blockIdx.x] + s[t] - tsum;
  int4 r;
  r.x = off; r.y = off + c.x; r.z = off + c.x + c.y; r.w = off + c.x + c.y + c.z;
  *(int4*)(row_ptr + base + t * 4) = r;
  *(int4*)(cursor + base + t * 4) = r;
}

__global__ __launch_bounds__(256) void ngnn97_fill(const int* __restrict__ src, const int* __restrict__ dst,
                                                   int* __restrict__ cursor, int* __restrict__ srcs) {
  int e = blockIdx.x * 256 + threadIdx.x;
  if (e < EE) {
    int pos = atomicAdd(&cursor[dst[e]], 1);
    srcs[pos] = src[e];
  }
}

// ---------------- node -> graph id precompute (uint8) ----------------
__global__ __launch_bounds__(256) void ngnn97_g8(const int* __restrict__ n2s, const int* __restrict__ s2g,
                                                 unsigned char* __restrict__ g8) {
  int idx = blockIdx.x * 256 + threadIdx.x;
  if (idx < NN) g8[idx] = (unsigned char)s2g[n2s[idx]];
}

// ---------------- bucket nodes by graph: LDS hist + two-pass fill ----------------
__global__ __launch_bounds__(256) void ngnn97_bucket(const unsigned char* __restrict__ g8,
                                                     int* __restrict__ gcur, int* __restrict__ nlist) {
  __shared__ int hcnt[64];
  __shared__ int hbase[64];
  int t = threadIdx.x;
  int base = blockIdx.x * 1024;
  if (t < 64) hcnt[t] = 0;
  __syncthreads();
#pragma unroll
  for (int i = 0; i < 4; i++) {
    int node = base + i * 256 + t;
    if (node < NN) atomicAdd(&hcnt[g8[node]], 1);
  }
  __syncthreads();
  if (t < 64) {
    int c = hcnt[t];
    hbase[t] = (c > 0) ? atomicAdd(&gcur[t], c) : 0;
    hcnt[t] = 0;
  }
  __syncthreads();
#pragma unroll
  for (int i = 0; i < 4; i++) {
    int node = base + i * 256 + t;
    if (node < NN) {
      int g = g8[node];
      int loc = atomicAdd(&hcnt[g], 1);
      int pos = hbase[g] + loc;
      if (pos < GCAP) nlist[g * GCAP + pos] = node;
    }
  }
}

// ---------------- layer-0 embedding: bf16x8 row copies from ztabh ----------------
__global__ __launch_bounds__(256) void ngnn97_embed(const int* __restrict__ z,
                                                    const unsigned short* __restrict__ ztabh,
                                                    unsigned short* __restrict__ xh) {
  int idx = blockIdx.x * 256 + threadIdx.x;
  int node = idx >> 3, sub = idx & 7;
  if (node < NN) {
    int zz = z[node];
    *(bf16x8*)(xh + (size_t)node * 64 + sub * 8) =
        *(const bf16x8*)(ztabh + zz * 64 + sub * 8);
  }
}

// ---------------- FUSED gather + GRU via MFMA (+ optional transform) ----------------
// Ping-pong: reads xh_old (complete from prev layer), writes xh_new.
// Block = 128 nodes, 4 waves; wave w owns strip [nbase+32w, +32) -> ZERO barriers.
// Gather keeps agg's 8-parallel-chain structure (4 sub-batches of 8 nodes/wave).
__global__ __launch_bounds__(256, 4) void ngnn97_gru(
    const unsigned short* __restrict__ xh_old, unsigned short* __restrict__ xh_new,
    const int* __restrict__ rowp, const int* __restrict__ srcs,
    const unsigned short* __restrict__ Ubt, const float* __restrict__ Ub,
    const unsigned short* __restrict__ Vbt, const float* __restrict__ tfb,
    const int* __restrict__ z, const unsigned short* __restrict__ ztabh,
    int do_transform) {
  __shared__ unsigned short Abuf[128 * 72];    // 18.4 KB: agg -> xh -> xn scratch
  const int t = threadIdx.x;
  const int lane = t & 63, w = t >> 6;
  const int ncol = lane & 15, quad = lane >> 4;
  const int nbase = blockIdx.x * 128;
  const int strip = 32 * w;

  // ---- gather: 4 sub-batches x 8 nodes, 8 lanes (sub) per node -> Abuf cols 0..63 ----
  {
    int grp = lane >> 3, sub = lane & 7;
#pragma unroll
    for (int sb = 0; sb < 4; sb++) {
      int row = strip + sb * 8 + grp;
      int node = nbase + row;
      float acc[8];
#pragma unroll
      for (int i = 0; i < 8; i++) acc[i] = 0.f;
      if (node < NN) {
        int b = rowp[node], e = rowp[node + 1];
        int p = b;
        for (; p + 2 <= e; p += 2) {
          int s0 = srcs[p], s1 = srcs[p + 1];
          bf16x8 v0 = *(const bf16x8*)(xh_old + (size_t)s0 * 64 + sub * 8);
          bf16x8 v1 = *(const bf16x8*)(xh_old + (size_t)s1 * 64 + sub * 8);
#pragma unroll
          for (int i = 0; i < 8; i++)
            acc[i] += ngnn97_bf2f((unsigned short)v0[i]) + ngnn97_bf2f((unsigned short)v1[i]);
        }
        if (p < e) {
          bf16x8 v0 = *(const bf16x8*)(xh_old + (size_t)srcs[p] * 64 + sub * 8);
#pragma unroll
          for (int i = 0; i < 8; i++) acc[i] += ngnn97_bf2f((unsigned short)v0[i]);
        }
      }
      bf16x8 ov;
#pragma unroll
      for (int i = 0; i < 8; i++) ov[i] = (short)ngnn97_f2bf(acc[i]);
      *(bf16x8*)(Abuf + row * 72 + sub * 8) = ov;
    }
  }

  // ---- afrA frags from gathered agg (same-wave DS ordering: reads before later writes) ----
  bf16x8 afrA[2][2];
#pragma unroll
  for (int mm = 0; mm < 2; mm++)
#pragma unroll
    for (int kc = 0; kc < 2; kc++)
      afrA[mm][kc] = *(const bf16x8*)(Abuf + (strip + mm * 16 + ncol) * 72 + quad * 8 + kc * 32);

  // ---- stage xh_old strip rows -> Abuf cols 0..63 (overwrite agg; in-order DS pipe) ----
#pragma unroll
  for (int i = 0; i < 8; i++) {
    int chunk = i * 64 + lane;                 // 512 = 32 rows x 16 ushort4
    int r2 = chunk >> 4, c4 = (chunk & 15) << 2;
    int node = nbase + strip + r2;
    ushort4 qx = make_ushort4(0, 0, 0, 0);
    if (node < NN) qx = *(const ushort4*)(xh_old + (size_t)node * 64 + c4);
    *(ushort4*)(Abuf + (strip + r2) * 72 + c4) = qx;
  }

  bf16x8 afrX[2][2];
#pragma unroll
  for (int mm = 0; mm < 2; mm++)
#pragma unroll
    for (int kc = 0; kc < 2; kc++)
      afrX[mm][kc] = *(const bf16x8*)(Abuf + (strip + mm * 16 + ncol) * 72 + quad * 8 + kc * 32);

  // ---- gate GEMM + GRU update; xn overwrites Abuf cols 0..63 ----
#pragma unroll
  for (int c = 0; c < 4; c++) {
    f32x4 aR[2], aZ[2], aN[2], aH[2];
#pragma unroll
    for (int mm = 0; mm < 2; mm++) {
      aR[mm] = (f32x4){0.f, 0.f, 0.f, 0.f}; aZ[mm] = aR[mm];
      aN[mm] = aR[mm]; aH[mm] = aR[mm];
    }
#pragma unroll
    for (int kc = 0; kc < 4; kc++) {
      const unsigned short* ub = Ubt + (size_t)(c * 16 + ncol) * 128 + quad * 8 + kc * 32;
      bf16x8 bR = *(const bf16x8*)(ub);
      bf16x8 bZ = *(const bf16x8*)(ub + 64 * 128);
      bf16x8 bX = (kc < 2) ? *(const bf16x8*)(ub + 128 * 128)
                           : *(const bf16x8*)(ub + 192 * 128);
#pragma unroll
      for (int mm = 0; mm < 2; mm++) {
        bf16x8 a = (kc < 2) ? afrA[mm][kc] : afrX[mm][kc - 2];
        aR[mm] = __builtin_amdgcn_mfma_f32_16x16x32_bf16(a, bR, aR[mm], 0, 0, 0);
        aZ[mm] = __builtin_amdgcn_mfma_f32_16x16x32_bf16(a, bZ, aZ[mm], 0, 0, 0);
        if (kc < 2) aN[mm] = __builtin_amdgcn_mfma_f32_16x16x32_bf16(a, bX, aN[mm], 0, 0, 0);
        else        aH[mm] = __builtin_amdgcn_mfma_f32_16x16x32_bf16(a, bX, aH[mm], 0, 0, 0);
      }
    }
    int j = c * 16 + ncol;
    float bRs = Ub[j], bZs = Ub[64 + j], bNs = Ub[128 + j], bHs = Ub[192 + j];
#pragma unroll
    for (int mm = 0; mm < 2; mm++)
#pragma unroll
      for (int r = 0; r < 4; r++) {
        int row = strip + mm * 16 + quad * 4 + r;
        float R = aR[mm][r] + bRs, Z = aZ[mm][r] + bZs;
        float Nv = aN[mm][r] + bNs, H = aH[mm][r] + bHs;
        float rg = 1.f / (1.f + __expf(-R));
        float ug = 1.f / (1.f + __expf(-Z));
        float e2 = __expf(2.f * (Nv + rg * H));
        float nn2 = 1.f - 2.f / (e2 + 1.f);    // tanh via fast exp (saturates safely)
        float xo = ngnn97_bf2f(Abuf[row * 72 + 64 + j - c * 16 + c * 16]);  // placeholder
        xo = ngnn97_bf2f(Abuf[row * 72 + j]);   // xh staged in cols 0..63
        Abuf[row * 72 + j] = ngnn97_f2bf((1.f - ug) * nn2 + ug * xo);
      }
  }

  if (do_transform) {
    // ---- A2-frags: xn from LDS, ze direct from bf16 ztab ----
    bf16x8 afrN[2][2], afrE[2][2];
#pragma unroll
    for (int mm = 0; mm < 2; mm++) {
      int node = nbase + strip + mm * 16 + ncol;
      int zz = (node < NN) ? z[node] : 0;
#pragma unroll
      for (int kc = 0; kc < 2; kc++) {
        afrN[mm][kc] = *(const bf16x8*)(Abuf + (strip + mm * 16 + ncol) * 72 + quad * 8 + kc * 32);
        afrE[mm][kc] = *(const bf16x8*)(ztabh + zz * 64 + quad * 8 + kc * 32);
      }
    }
    // ---- transform GEMM -> Abuf cols 0..63 ----
#pragma unroll
    for (int c2 = 0; c2 < 4; c2++) {
      f32x4 acc[2];
      acc[0] = (f32x4){0.f, 0.f, 0.f, 0.f}; acc[1] = acc[0];
#pragma unroll
      for (int kc = 0; kc < 4; kc++) {
        bf16x8 bV = *(const bf16x8*)(Vbt + (size_t)(c2 * 16 + ncol) * 128 + quad * 8 + kc * 32);
#pragma unroll
        for (int mm = 0; mm < 2; mm++) {
          bf16x8 a = (kc < 2) ? afrN[mm][kc] : afrE[mm][kc - 2];
          acc[mm] = __builtin_amdgcn_mfma_f32_16x16x32_bf16(a, bV, acc[mm], 0, 0, 0);
        }
      }
      int j = c2 * 16 + ncol;
      float bt = tfb[j];
#pragma unroll
      for (int mm = 0; mm < 2; mm++)
#pragma unroll
        for (int r = 0; r < 4; r++) {
          int row = strip + mm * 16 + quad * 4 + r;
          Abuf[row * 72 + j] = ngnn97_f2bf(acc[mm][r] + bt);
        }
    }
  }

  // ---- coalesced store: Abuf cols 0..63 (strip) -> xh_new ----
#pragma unroll
  for (int i = 0; i < 8; i++) {
    int chunk = i * 64 + lane;
    int r2 = chunk >> 4, c4 = (chunk & 15) << 2;
    int node = nbase + strip + r2;
    if (node < NN)
      *(ushort4*)(xh_new + (size_t)node * 64 + c4) = *(const ushort4*)(Abuf + (strip + r2) * 72 + c4);
  }
}

// ---------------- pooling: bucketed contiguous reduction ----------------
__global__ __launch_bounds__(256) void ngnn97_pool(const unsigned short* __restrict__ xh,
                                                   const int* __restrict__ nlist,
                                                   const int* __restrict__ gcur,
                                                   float* __restrict__ gpool) {
  __shared__ float part[4][64];
  int t = threadIdx.x;
  int lane = t & 63, wv = t >> 6;
  int g = blockIdx.x >> 4, c = blockIdx.x & 15;
  int cnt = gcur[g];
  if (cnt > GCAP) cnt = GCAP;
  int r0 = (c * cnt) >> 4, r1 = ((c + 1) * cnt) >> 4;
  const int* nl = nlist + g * GCAP;
  float a0 = 0.f, a1 = 0.f;
  int r = r0 + wv;
  for (; r + 4 < r1; r += 8) {
    int n0 = nl[r], n1 = nl[r + 4];
    a0 += ngnn97_bf2f(xh[(size_t)n0 * 64 + lane]);
    a1 += ngnn97_bf2f(xh[(size_t)n1 * 64 + lane]);
  }
  if (r < r1) a0 += ngnn97_bf2f(xh[(size_t)nl[r] * 64 + lane]);
  part[wv][lane] = a0 + a1;
  __syncthreads();
  if (t < 64)
    atomicAdd(&gpool[g * 64 + t], part[0][t] + part[1][t] + part[2][t] + part[3][t]);
}

// ---------------- MLP head (output: float32 [G,1]) ----------------
__global__ __launch_bounds__(256) void ngnn97_head(
    const float* __restrict__ gpool,
    const float* __restrict__ W1, const float* __restrict__ b1,
    const float* __restrict__ W2, const float* __restrict__ b2,
    const float* __restrict__ W3, const float* __restrict__ b3,
    float* __restrict__ out) {
  __shared__ float gp[4096];
  __shared__ float h1[2048];
  __shared__ float h2[1024];
  int t = threadIdx.x;
  for (int i = t; i < 4096; i += 256) gp[i] = gpool[i];
  __syncthreads();
  for (int i = t; i < 2048; i += 256) {
    int g = i >> 5, o = i & 31;
    float a = b1[o];
    for (int d = 0; d < 64; d++) a = fmaf(gp[g * 64 + d], W1[o * 64 + d], a);
    h1[i] = (a > 0.f) ? a : (__expf(a) - 1.f);
  }
  __syncthreads();
  for (int i = t; i < 1024; i += 256) {
    int g = i >> 4, o = i & 15;
    float a = b2[o];
    for (int d = 0; d < 32; d++) a = fmaf(h1[g * 32 + d], W2[o * 32 + d], a);
    h2[i] = (a > 0.f) ? a : (__expf(a) - 1.f);
  }
  __syncthreads();
  if (t < 64) {
    float a = b3[0];
    for (int d = 0; d < 16; d++) a = fmaf(h2[t * 16 + d], W3[d], a);
    out[t] = a;
  }
}

// ---------------- workspace layout (byte offsets) ----------------
#define OFF_XH0   ((size_t)0)                          // N*64 bf16 = 64,000,000
#define OFF_XH1   ((size_t)64000000)                   // N*64 bf16 = 64,000,000
#define OFF_CNT   ((size_t)128000000)                  // NP int
#define OFF_ROW   (OFF_CNT + (size_t)NP * 4)
#define OFF_CUR   (OFF_ROW + (size_t)NP * 4)
#define OFF_SRC   (OFF_CUR + (size_t)NP * 4)           // E int
#define OFF_BSUM  (OFF_SRC + (size_t)EE * 4)
#define OFF_BOFF  (OFF_BSUM + (size_t)2048)
#define OFF_U     (OFF_BOFF + (size_t)2048)            // Ubt bf16 5*256*128
#define OFF_UB    (OFF_U + (size_t)327680)             // Ub f32 5*256
#define OFF_V     (OFF_UB + (size_t)5120)              // Vbt bf16 4*64*128
#define OFF_GP    (OFF_V + (size_t)65536)              // gpool 64*64 f32
#define OFF_G8    (OFF_GP + (size_t)16384)             // N uint8 (padded)
#define OFF_ZTH   (OFF_G8 + (size_t)500736)            // ztabh bf16 5*100*64
#define OFF_GCUR  (OFF_ZTH + (size_t)64000)            // 64 ints (+pad)
#define OFF_NL    (OFF_GCUR + (size_t)1024)            // nlist 64*GCAP ints = 4 MB
#define WS_NEED   (OFF_NL + (size_t)64 * GCAP * 4)     // ~= 144.2 MB (proven budget 203.8)

extern "C" void kernel_launch(void* const* d_in, const int* in_sizes, int n_in,
                              void* d_out, int out_size, void* d_ws, size_t ws_size,
                              hipStream_t stream) {
  float* out = (float*)d_out;   // reference output is float32 [G,1]
  if (ws_size < WS_NEED) {
    ngnn97_code<<<1, 64, 0, stream>>>(out, 7.0f);
    return;
  }

  const int* z    = (const int*)d_in[0];
  const int* ei   = (const int*)d_in[1];
  const int* n2s  = (const int*)d_in[2];
  const int* s2g  = (const int*)d_in[3];
  const float* ztab = (const float*)d_in[4];
  const float* tfW  = (const float*)d_in[5];
  const float* tfb  = (const float*)d_in[6];
  const float* ggc  = (const float*)d_in[7];
  const float* wih  = (const float*)d_in[8];
  const float* whh  = (const float*)d_in[9];
  const float* bih  = (const float*)d_in[10];
  const float* bhh  = (const float*)d_in[11];
  const float* W1   = (const float*)d_in[12];
  const float* b1   = (const float*)d_in[13];
  const float* W2   = (const float*)d_in[14];
  const float* b2   = (const float*)d_in[15];
  const float* W3   = (const float*)d_in[16];
  const float* b3   = (const float*)d_in[17];

  char* ws = (char*)d_ws;
  unsigned short* xh0    = (unsigned short*)(ws + OFF_XH0);
  unsigned short* xh1    = (unsigned short*)(ws + OFF_XH1);
  int*            counts = (int*)(ws + OFF_CNT);
  int*            rowp   = (int*)(ws + OFF_ROW);
  int*            curs   = (int*)(ws + OFF_CUR);
  int*            srcs   = (int*)(ws + OFF_SRC);
  int*            bsum   = (int*)(ws + OFF_BSUM);
  int*            boff   = (int*)(ws + OFF_BOFF);
  unsigned short* Ubt    = (unsigned short*)(ws + OFF_U);
  float*          Ub     = (float*)(ws + OFF_UB);
  unsigned short* Vbt    = (unsigned short*)(ws + OFF_V);
  float*          gpool  = (float*)(ws + OFF_GP);
  unsigned char*  g8     = (unsigned char*)(ws + OFF_G8);
  unsigned short* ztabh  = (unsigned short*)(ws + OFF_ZTH);
  int*            gcur   = (int*)(ws + OFF_GCUR);
  int*            nlist  = (int*)(ws + OFF_NL);

  hipMemsetAsync(counts, 0, (size_t)NP * 4, stream);
  hipMemsetAsync(gpool, 0, 16384, stream);
  hipMemsetAsync(gcur, 0, 1024, stream);

  ngnn97_pre<<<899, 256, 0, stream>>>(ggc, wih, whh, bih, bhh, tfW, ztab, Ubt, Ub, Vbt, ztabh);
  ngnn97_g8<<<(NN + 255) / 256, 256, 0, stream>>>(n2s, s2g, g8);
  ngnn97_bucket<<<NBLK, 256, 0, stream>>>(g8, gcur, nlist);

  // CSR by dst
  const int* srcp = ei;
  const int* dstp = ei + EE;
  ngnn97_hist<<<(EE + 255) / 256, 256, 0, stream>>>(dstp, counts);
  ngnn97_red<<<NBLK, 256, 0, stream>>>(counts, bsum);
  ngnn97_scan1<<<1, 512, 0, stream>>>(bsum, boff);
  ngnn97_scan2<<<NBLK, 256, 0, stream>>>(counts, boff, rowp, curs);
  ngnn97_fill<<<(EE + 255) / 256, 256, 0, stream>>>(srcp, dstp, curs, srcs);
  // rowp[n]..rowp[n+1] bounds node n's incoming-edge list

  ngnn97_embed<<<(NN * 8 + 255) / 256, 256, 0, stream>>>(z, ztabh, xh0);

  unsigned short* xc = xh0;
  unsigned short* xn2 = xh1;
  for (int l = 0; l < 5; l++) {
    ngnn97_gru<<<(NN + 127) / 128, 256, 0, stream>>>(
        xc, xn2, rowp, srcs,
        Ubt + (size_t)l * 32768, Ub + (size_t)l * 256,
        Vbt + (size_t)(l < 4 ? l : 0) * 8192, tfb + (size_t)(l < 4 ? l : 0) * 64,
        z, ztabh + (size_t)(l < 4 ? l + 1 : 0) * 6400, (l < 4) ? 1 : 0);
    unsigned short* tmp = xc; xc = xn2; xn2 = tmp;
  }
  // final state in xc

  ngnn97_pool<<<1024, 256, 0, stream>>>(xc, nlist, gcur, gpool);
  ngnn97_head<<<1, 256, 0, stream>>>(gpool, W1, b1, W2, b2, W3, b3, out);
}

// Round 19
// 1105.532 us; speedup vs baseline: 1.2258x; 1.0527x over previous
//
#include <hip/hip_runtime.h>
#include <hip/hip_bf16.h>

// ---------------- problem constants ----------------
#define NN 500000
#define EE 1250000
#define NP 501760          // padded node count
#define NBLK 489           // scan blocks of 1024
#define GCAP 16384         // nlist capacity per graph (expected 7812, 2.1x margin)

typedef __attribute__((ext_vector_type(8))) short bf16x8;
typedef __attribute__((ext_vector_type(4))) float f32x4;

__device__ __forceinline__ float ngnn97_bf2f(unsigned short u) {
  return __uint_as_float(((unsigned int)u) << 16);
}
__device__ __forceinline__ unsigned short ngnn97_f2bf(float f) {
  union { __hip_bfloat16 b; unsigned short u; } cv;
  cv.b = __float2bfloat16(f);
  return cv.u;
}
// accumulate 4 dwords (8 bf16) into lo/hi f32 accumulators, dword-wise
__device__ __forceinline__ void ngnn97_acc8(uint4 u, float* lo, float* hi) {
  lo[0] += __uint_as_float(u.x << 16); hi[0] += __uint_as_float(u.x & 0xFFFF0000u);
  lo[1] += __uint_as_float(u.y << 16); hi[1] += __uint_as_float(u.y & 0xFFFF0000u);
  lo[2] += __uint_as_float(u.z << 16); hi[2] += __uint_as_float(u.z & 0xFFFF0000u);
  lo[3] += __uint_as_float(u.w << 16); hi[3] += __uint_as_float(u.w & 0xFFFF0000u);
}

// ---------------- diagnostic code writer (guard path only) ----------------
__global__ void ngnn97_code(float* __restrict__ out, float v) {
  if (threadIdx.x < 64) out[threadIdx.x] = v;
}

// ---------------- precompute folded weights (bf16, MFMA-B layout) + bf16 ztab ----------------
__global__ __launch_bounds__(256) void ngnn97_pre(
    const float* __restrict__ ggc, const float* __restrict__ wih,
    const float* __restrict__ whh, const float* __restrict__ bih,
    const float* __restrict__ bhh, const float* __restrict__ tfW,
    const float* __restrict__ ztab,
    unsigned short* __restrict__ Ubt, float* __restrict__ Ub,
    unsigned short* __restrict__ Vbt, unsigned short* __restrict__ ztabh) {
  int idx = blockIdx.x * 256 + threadIdx.x;
  if (idx < 163840) {                      // Ubt: 5*256*128
    int l = idx >> 15, r = idx & 32767;
    int n = r >> 7, k = r & 127;
    float v = 0.f;
    if (k < 64) {
      if (n < 192) {
        const float* gp = ggc + l * 4096 + k * 64;
        const float* wp = wih + l * 12288 + n * 64;
        float acc = 0.f;
#pragma unroll
        for (int t2 = 0; t2 < 64; t2++) acc = fmaf(gp[t2], wp[t2], acc);
        v = acc;
      }
    } else {
      int k2 = k - 64;
      if (n < 128) v = whh[l * 12288 + n * 64 + k2];
      else if (n >= 192) v = whh[l * 12288 + (n - 64) * 64 + k2];
    }
    Ubt[idx] = ngnn97_f2bf(v);
  } else if (idx < 196608) {               // Vbt: 4*64*128 (= tfW flat)
    int i2 = idx - 163840;
    Vbt[i2] = ngnn97_f2bf(tfW[i2]);
  } else if (idx < 197888) {               // Ub: 5*256
    int i2 = idx - 196608;
    int l = i2 >> 8, j = i2 & 255;
    float v;
    if (j < 128)      v = bih[l * 192 + j] + bhh[l * 192 + j];
    else if (j < 192) v = bih[l * 192 + j];
    else              v = bhh[l * 192 + j - 64];
    Ub[i2] = v;
  } else if (idx < 229888) {               // ztabh: 5*100*64 bf16
    int i2 = idx - 197888;
    ztabh[i2] = ngnn97_f2bf(ztab[i2]);
  }
}

// ---------------- CSR build ----------------
__global__ __launch_bounds__(256) void ngnn97_hist(const int* __restrict__ dst, int* __restrict__ counts) {
  int e = blockIdx.x * 256 + threadIdx.x;
  if (e < EE) atomicAdd(&counts[dst[e]], 1);
}

__global__ __launch_bounds__(256) void ngnn97_red(const int* __restrict__ counts, int* __restrict__ bsum) {
  __shared__ int s[256];
  int t = threadIdx.x, base = blockIdx.x * 1024;
  int v = 0;
#pragma unroll
  for (int i = 0; i < 4; i++) v += counts[base + t + i * 256];
  s[t] = v; __syncthreads();
  for (int o = 128; o > 0; o >>= 1) { if (t < o) s[t] += s[t + o]; __syncthreads(); }
  if (t == 0) bsum[blockIdx.x] = s[0];
}

__global__ __launch_bounds__(512) void ngnn97_scan1(const int* __restrict__ bsum, int* __restrict__ boff) {
  __shared__ int s[512];
  int t = threadIdx.x;
  int v = (t < NBLK) ? bsum[t] : 0;
  s[t] = v; __syncthreads();
  for (int o = 1; o < 512; o <<= 1) {
    int a = (t >= o) ? s[t - o] : 0;
    __syncthreads(); s[t] += a; __syncthreads();
  }
  if (t < NBLK) boff[t] = s[t] - v;   // exclusive
}

__global__ __launch_bounds__(256) void ngnn97_scan2(const int* __restrict__ counts, const int* __restrict__ boff,
                                                    int* __restrict__ row_ptr, int* __restrict__ cursor) {
  __shared__ int s[256];
  int t = threadIdx.x, base = blockIdx.x * 1024;
  int4 c = *(const int4*)(counts + base + t * 4);
  int tsum = c.x + c.y + c.z + c.w;
  s[t] = tsum; __syncthreads();
  for (int o = 1; o < 256; o <<= 1) {
    int a = (t >= o) ? s[t - o] : 0;
    __syncthreads(); s[t] += a; __syncthreads();
  }
  int off = boff[blockIdx.x] + s[t] - tsum;
  int4 r;
  r.x = off; r.y = off + c.x; r.z = off + c.x + c.y; r.w = off + c.x + c.y + c.z;
  *(int4*)(row_ptr + base + t * 4) = r;
  *(int4*)(cursor + base + t * 4) = r;
}

__global__ __launch_bounds__(256) void ngnn97_fill(const int* __restrict__ src, const int* __restrict__ dst,
                                                   int* __restrict__ cursor, int* __restrict__ srcs) {
  int e = blockIdx.x * 256 + threadIdx.x;
  if (e < EE) {
    int pos = atomicAdd(&cursor[dst[e]], 1);
    srcs[pos] = src[e];
  }
}

// ---------------- node -> graph id precompute (uint8) ----------------
__global__ __launch_bounds__(256) void ngnn97_g8(const int* __restrict__ n2s, const int* __restrict__ s2g,
                                                 unsigned char* __restrict__ g8) {
  int idx = blockIdx.x * 256 + threadIdx.x;
  if (idx < NN) g8[idx] = (unsigned char)s2g[n2s[idx]];
}

// ---------------- bucket nodes by graph: LDS hist + two-pass fill ----------------
__global__ __launch_bounds__(256) void ngnn97_bucket(const unsigned char* __restrict__ g8,
                                                     int* __restrict__ gcur, int* __restrict__ nlist) {
  __shared__ int hcnt[64];
  __shared__ int hbase[64];
  int t = threadIdx.x;
  int base = blockIdx.x * 1024;
  if (t < 64) hcnt[t] = 0;
  __syncthreads();
#pragma unroll
  for (int i = 0; i < 4; i++) {
    int node = base + i * 256 + t;
    if (node < NN) atomicAdd(&hcnt[g8[node]], 1);
  }
  __syncthreads();
  if (t < 64) {
    int c = hcnt[t];
    hbase[t] = (c > 0) ? atomicAdd(&gcur[t], c) : 0;
    hcnt[t] = 0;
  }
  __syncthreads();
#pragma unroll
  for (int i = 0; i < 4; i++) {
    int node = base + i * 256 + t;
    if (node < NN) {
      int g = g8[node];
      int loc = atomicAdd(&hcnt[g], 1);
      int pos = hbase[g] + loc;
      if (pos < GCAP) nlist[g * GCAP + pos] = node;
    }
  }
}

// ---------------- layer-0 embedding: bf16x8 row copies from ztabh ----------------
__global__ __launch_bounds__(256) void ngnn97_embed(const int* __restrict__ z,
                                                    const unsigned short* __restrict__ ztabh,
                                                    unsigned short* __restrict__ xh) {
  int idx = blockIdx.x * 256 + threadIdx.x;
  int node = idx >> 3, sub = idx & 7;
  if (node < NN) {
    int zz = z[node];
    *(bf16x8*)(xh + (size_t)node * 64 + sub * 8) =
        *(const bf16x8*)(ztabh + zz * 64 + sub * 8);
  }
}

// ---------------- FUSED gather + GRU via MFMA (+ optional transform) ----------------
// Ping-pong: reads xh_old (complete from prev layer), writes xh_new.
// Block = 128 nodes, 4 waves; wave w owns strip [nbase+32w, +32) -> ZERO barriers.
// Gather: 16 node-chains per wave (4 lanes/node), dword-wise bf16 accumulation.
__global__ __launch_bounds__(256, 4) void ngnn97_gru(
    const unsigned short* __restrict__ xh_old, unsigned short* __restrict__ xh_new,
    const int* __restrict__ rowp, const int* __restrict__ srcs,
    const unsigned short* __restrict__ Ubt, const float* __restrict__ Ub,
    const unsigned short* __restrict__ Vbt, const float* __restrict__ tfb,
    const int* __restrict__ z, const unsigned short* __restrict__ ztabh,
    int do_transform) {
  __shared__ unsigned short Abuf[128 * 72];    // 18.4 KB: agg -> xh -> xn scratch
  const int t = threadIdx.x;
  const int lane = t & 63, w = t >> 6;
  const int ncol = lane & 15, quad = lane >> 4;
  const int nbase = blockIdx.x * 128;
  const int strip = 32 * w;

  // ---- gather: 2 sub-batches x 16 nodes, 4 lanes (sub) per node -> Abuf cols 0..63 ----
  {
    int grp = lane >> 2, sub = lane & 2 * 2;   // grp 0..15
    sub = lane & 3;                            // sub 0..3: elems [sub*16, +16)
#pragma unroll
    for (int sb = 0; sb < 2; sb++) {
      int row = strip + sb * 16 + grp;
      int node = nbase + row;
      float lo[8], hi[8];
#pragma unroll
      for (int i = 0; i < 8; i++) { lo[i] = 0.f; hi[i] = 0.f; }
      if (node < NN) {
        int b = rowp[node], e = rowp[node + 1];
        int p = b;
        for (; p + 2 <= e; p += 2) {
          int s0 = srcs[p], s1 = srcs[p + 1];
          const unsigned short* r0 = xh_old + (size_t)s0 * 64 + sub * 16;
          const unsigned short* r1 = xh_old + (size_t)s1 * 64 + sub * 16;
          uint4 u0 = *(const uint4*)(r0);
          uint4 u1 = *(const uint4*)(r0 + 8);
          uint4 u2 = *(const uint4*)(r1);
          uint4 u3 = *(const uint4*)(r1 + 8);
          ngnn97_acc8(u0, lo, hi);
          ngnn97_acc8(u1, lo + 4, hi + 4);
          ngnn97_acc8(u2, lo, hi);
          ngnn97_acc8(u3, lo + 4, hi + 4);
        }
        if (p < e) {
          const unsigned short* r0 = xh_old + (size_t)srcs[p] * 64 + sub * 16;
          uint4 u0 = *(const uint4*)(r0);
          uint4 u1 = *(const uint4*)(r0 + 8);
          ngnn97_acc8(u0, lo, hi);
          ngnn97_acc8(u1, lo + 4, hi + 4);
        }
      }
      // pack: dword j of chunk c -> elements (c*8+2j, c*8+2j+1) = (lo, hi)
#pragma unroll
      for (int c = 0; c < 2; c++) {
        bf16x8 ov;
#pragma unroll
        for (int j = 0; j < 4; j++) {
          ov[2 * j]     = (short)ngnn97_f2bf(lo[c * 4 + j]);
          ov[2 * j + 1] = (short)ngnn97_f2bf(hi[c * 4 + j]);
        }
        *(bf16x8*)(Abuf + row * 72 + sub * 16 + c * 8) = ov;
      }
    }
  }

  // ---- afrA frags from gathered agg (same-wave DS ordering: reads after own writes) ----
  bf16x8 afrA[2][2];
#pragma unroll
  for (int mm = 0; mm < 2; mm++)
#pragma unroll
    for (int kc = 0; kc < 2; kc++)
      afrA[mm][kc] = *(const bf16x8*)(Abuf + (strip + mm * 16 + ncol) * 72 + quad * 8 + kc * 32);

  // ---- stage xh_old strip rows -> Abuf cols 0..63 (overwrite agg; in-order DS pipe) ----
#pragma unroll
  for (int i = 0; i < 8; i++) {
    int chunk = i * 64 + lane;                 // 512 = 32 rows x 16 ushort4
    int r2 = chunk >> 4, c4 = (chunk & 15) << 2;
    int node = nbase + strip + r2;
    ushort4 qx = make_ushort4(0, 0, 0, 0);
    if (node < NN) qx = *(const ushort4*)(xh_old + (size_t)node * 64 + c4);
    *(ushort4*)(Abuf + (strip + r2) * 72 + c4) = qx;
  }

  bf16x8 afrX[2][2];
#pragma unroll
  for (int mm = 0; mm < 2; mm++)
#pragma unroll
    for (int kc = 0; kc < 2; kc++)
      afrX[mm][kc] = *(const bf16x8*)(Abuf + (strip + mm * 16 + ncol) * 72 + quad * 8 + kc * 32);

  // ---- gate GEMM + GRU update; xn overwrites Abuf cols 0..63 ----
#pragma unroll
  for (int c = 0; c < 4; c++) {
    f32x4 aR[2], aZ[2], aN[2], aH[2];
#pragma unroll
    for (int mm = 0; mm < 2; mm++) {
      aR[mm] = (f32x4){0.f, 0.f, 0.f, 0.f}; aZ[mm] = aR[mm];
      aN[mm] = aR[mm]; aH[mm] = aR[mm];
    }
#pragma unroll
    for (int kc = 0; kc < 4; kc++) {
      const unsigned short* ub = Ubt + (size_t)(c * 16 + ncol) * 128 + quad * 8 + kc * 32;
      bf16x8 bR = *(const bf16x8*)(ub);
      bf16x8 bZ = *(const bf16x8*)(ub + 64 * 128);
      bf16x8 bX = (kc < 2) ? *(const bf16x8*)(ub + 128 * 128)
                           : *(const bf16x8*)(ub + 192 * 128);
#pragma unroll
      for (int mm = 0; mm < 2; mm++) {
        bf16x8 a = (kc < 2) ? afrA[mm][kc] : afrX[mm][kc - 2];
        aR[mm] = __builtin_amdgcn_mfma_f32_16x16x32_bf16(a, bR, aR[mm], 0, 0, 0);
        aZ[mm] = __builtin_amdgcn_mfma_f32_16x16x32_bf16(a, bZ, aZ[mm], 0, 0, 0);
        if (kc < 2) aN[mm] = __builtin_amdgcn_mfma_f32_16x16x32_bf16(a, bX, aN[mm], 0, 0, 0);
        else        aH[mm] = __builtin_amdgcn_mfma_f32_16x16x32_bf16(a, bX, aH[mm], 0, 0, 0);
      }
    }
    int j = c * 16 + ncol;
    float bRs = Ub[j], bZs = Ub[64 + j], bNs = Ub[128 + j], bHs = Ub[192 + j];
#pragma unroll
    for (int mm = 0; mm < 2; mm++)
#pragma unroll
      for (int r = 0; r < 4; r++) {
        int row = strip + mm * 16 + quad * 4 + r;
        float R = aR[mm][r] + bRs, Z = aZ[mm][r] + bZs;
        float Nv = aN[mm][r] + bNs, H = aH[mm][r] + bHs;
        float rg = 1.f / (1.f + __expf(-R));
        float ug = 1.f / (1.f + __expf(-Z));
        float e2 = __expf(2.f * (Nv + rg * H));
        float nn2 = 1.f - 2.f / (e2 + 1.f);    // tanh via fast exp (saturates safely)
        float xo = ngnn97_bf2f(Abuf[row * 72 + j]);   // xh staged in cols 0..63
        Abuf[row * 72 + j] = ngnn97_f2bf((1.f - ug) * nn2 + ug * xo);
      }
  }

  if (do_transform) {
    // ---- A2-frags: xn from LDS, ze direct from bf16 ztab ----
    bf16x8 afrN[2][2], afrE[2][2];
#pragma unroll
    for (int mm = 0; mm < 2; mm++) {
      int node = nbase + strip + mm * 16 + ncol;
      int zz = (node < NN) ? z[node] : 0;
#pragma unroll
      for (int kc = 0; kc < 2; kc++) {
        afrN[mm][kc] = *(const bf16x8*)(Abuf + (strip + mm * 16 + ncol) * 72 + quad * 8 + kc * 32);
        afrE[mm][kc] = *(const bf16x8*)(ztabh + zz * 64 + quad * 8 + kc * 32);
      }
    }
    // ---- transform GEMM -> Abuf cols 0..63 ----
#pragma unroll
    for (int c2 = 0; c2 < 4; c2++) {
      f32x4 acc[2];
      acc[0] = (f32x4){0.f, 0.f, 0.f, 0.f}; acc[1] = acc[0];
#pragma unroll
      for (int kc = 0; kc < 4; kc++) {
        bf16x8 bV = *(const bf16x8*)(Vbt + (size_t)(c2 * 16 + ncol) * 128 + quad * 8 + kc * 32);
#pragma unroll
        for (int mm = 0; mm < 2; mm++) {
          bf16x8 a = (kc < 2) ? afrN[mm][kc] : afrE[mm][kc - 2];
          acc[mm] = __builtin_amdgcn_mfma_f32_16x16x32_bf16(a, bV, acc[mm], 0, 0, 0);
        }
      }
      int j = c2 * 16 + ncol;
      float bt = tfb[j];
#pragma unroll
      for (int mm = 0; mm < 2; mm++)
#pragma unroll
        for (int r = 0; r < 4; r++) {
          int row = strip + mm * 16 + quad * 4 + r;
          Abuf[row * 72 + j] = ngnn97_f2bf(acc[mm][r] + bt);
        }
    }
  }

  // ---- coalesced store: Abuf cols 0..63 (strip) -> xh_new ----
#pragma unroll
  for (int i = 0; i < 8; i++) {
    int chunk = i * 64 + lane;
    int r2 = chunk >> 4, c4 = (chunk & 15) << 2;
    int node = nbase + strip + r2;
    if (node < NN)
      *(ushort4*)(xh_new + (size_t)node * 64 + c4) = *(const ushort4*)(Abuf + (strip + r2) * 72 + c4);
  }
}

// ---------------- pooling: bucketed contiguous reduction ----------------
__global__ __launch_bounds__(256) void ngnn97_pool(const unsigned short* __restrict__ xh,
                                                   const int* __restrict__ nlist,
                                                   const int* __restrict__ gcur,
                                                   float* __restrict__ gpool) {
  __shared__ float part[4][64];
  int t = threadIdx.x;
  int lane = t & 63, wv = t >> 6;
  int g = blockIdx.x >> 4, c = blockIdx.x & 15;
  int cnt = gcur[g];
  if (cnt > GCAP) cnt = GCAP;
  int r0 = (c * cnt) >> 4, r1 = ((c + 1) * cnt) >> 4;
  const int* nl = nlist + g * GCAP;
  float a0 = 0.f, a1 = 0.f;
  int r = r0 + wv;
  for (; r + 4 < r1; r += 8) {
    int n0 = nl[r], n1 = nl[r + 4];
    a0 += ngnn97_bf2f(xh[(size_t)n0 * 64 + lane]);
    a1 += ngnn97_bf2f(xh[(size_t)n1 * 64 + lane]);
  }
  if (r < r1) a0 += ngnn97_bf2f(xh[(size_t)nl[r] * 64 + lane]);
  part[wv][lane] = a0 + a1;
  __syncthreads();
  if (t < 64)
    atomicAdd(&gpool[g * 64 + t], part[0][t] + part[1][t] + part[2][t] + part[3][t]);
}

// ---------------- MLP head (output: float32 [G,1]) ----------------
__global__ __launch_bounds__(256) void ngnn97_head(
    const float* __restrict__ gpool,
    const float* __restrict__ W1, const float* __restrict__ b1,
    const float* __restrict__ W2, const float* __restrict__ b2,
    const float* __restrict__ W3, const float* __restrict__ b3,
    float* __restrict__ out) {
  __shared__ float gp[4096];
  __shared__ float h1[2048];
  __shared__ float h2[1024];
  int t = threadIdx.x;
  for (int i = t; i < 4096; i += 256) gp[i] = gpool[i];
  __syncthreads();
  for (int i = t; i < 2048; i += 256) {
    int g = i >> 5, o = i & 31;
    float a = b1[o];
    for (int d = 0; d < 64; d++) a = fmaf(gp[g * 64 + d], W1[o * 64 + d], a);
    h1[i] = (a > 0.f) ? a : (__expf(a) - 1.f);
  }
  __syncthreads();
  for (int i = t; i < 1024; i += 256) {
    int g = i >> 4, o = i & 15;
    float a = b2[o];
    for (int d = 0; d < 32; d++) a = fmaf(h1[g * 32 + d], W2[o * 32 + d], a);
    h2[i] = (a > 0.f) ? a : (__expf(a) - 1.f);
  }
  __syncthreads();
  if (t < 64) {
    float a = b3[0];
    for (int d = 0; d < 16; d++) a = fmaf(h2[t * 16 + d], W3[d], a);
    out[t] = a;
  }
}

// ---------------- workspace layout (byte offsets) ----------------
#define OFF_XH0   ((size_t)0)                          // N*64 bf16 = 64,000,000
#define OFF_XH1   ((size_t)64000000)                   // N*64 bf16 = 64,000,000
#define OFF_CNT   ((size_t)128000000)                  // NP int
#define OFF_ROW   (OFF_CNT + (size_t)NP * 4)
#define OFF_CUR   (OFF_ROW + (size_t)NP * 4)
#define OFF_SRC   (OFF_CUR + (size_t)NP * 4)           // E int
#define OFF_BSUM  (OFF_SRC + (size_t)EE * 4)
#define OFF_BOFF  (OFF_BSUM + (size_t)2048)
#define OFF_U     (OFF_BOFF + (size_t)2048)            // Ubt bf16 5*256*128
#define OFF_UB    (OFF_U + (size_t)327680)             // Ub f32 5*256
#define OFF_V     (OFF_UB + (size_t)5120)              // Vbt bf16 4*64*128
#define OFF_GP    (OFF_V + (size_t)65536)              // gpool 64*64 f32
#define OFF_G8    (OFF_GP + (size_t)16384)             // N uint8 (padded)
#define OFF_ZTH   (OFF_G8 + (size_t)500736)            // ztabh bf16 5*100*64
#define OFF_GCUR  (OFF_ZTH + (size_t)64000)            // 64 ints (+pad)
#define OFF_NL    (OFF_GCUR + (size_t)1024)            // nlist 64*GCAP ints = 4 MB
#define WS_NEED   (OFF_NL + (size_t)64 * GCAP * 4)     // ~= 144.2 MB (proven budget 203.8)

extern "C" void kernel_launch(void* const* d_in, const int* in_sizes, int n_in,
                              void* d_out, int out_size, void* d_ws, size_t ws_size,
                              hipStream_t stream) {
  float* out = (float*)d_out;   // reference output is float32 [G,1]
  if (ws_size < WS_NEED) {
    ngnn97_code<<<1, 64, 0, stream>>>(out, 7.0f);
    return;
  }

  const int* z    = (const int*)d_in[0];
  const int* ei   = (const int*)d_in[1];
  const int* n2s  = (const int*)d_in[2];
  const int* s2g  = (const int*)d_in[3];
  const float* ztab = (const float*)d_in[4];
  const float* tfW  = (const float*)d_in[5];
  const float* tfb  = (const float*)d_in[6];
  const float* ggc  = (const float*)d_in[7];
  const float* wih  = (const float*)d_in[8];
  const float* whh  = (const float*)d_in[9];
  const float* bih  = (const float*)d_in[10];
  const float* bhh  = (const float*)d_in[11];
  const float* W1   = (const float*)d_in[12];
  const float* b1   = (const float*)d_in[13];
  const float* W2   = (const float*)d_in[14];
  const float* b2   = (const float*)d_in[15];
  const float* W3   = (const float*)d_in[16];
  const float* b3   = (const float*)d_in[17];

  char* ws = (char*)d_ws;
  unsigned short* xh0    = (unsigned short*)(ws + OFF_XH0);
  unsigned short* xh1    = (unsigned short*)(ws + OFF_XH1);
  int*            counts = (int*)(ws + OFF_CNT);
  int*            rowp   = (int*)(ws + OFF_ROW);
  int*            curs   = (int*)(ws + OFF_CUR);
  int*            srcs   = (int*)(ws + OFF_SRC);
  int*            bsum   = (int*)(ws + OFF_BSUM);
  int*            boff   = (int*)(ws + OFF_BOFF);
  unsigned short* Ubt    = (unsigned short*)(ws + OFF_U);
  float*          Ub     = (float*)(ws + OFF_UB);
  unsigned short* Vbt    = (unsigned short*)(ws + OFF_V);
  float*          gpool  = (float*)(ws + OFF_GP);
  unsigned char*  g8     = (unsigned char*)(ws + OFF_G8);
  unsigned short* ztabh  = (unsigned short*)(ws + OFF_ZTH);
  int*            gcur   = (int*)(ws + OFF_GCUR);
  int*            nlist  = (int*)(ws + OFF_NL);

  hipMemsetAsync(counts, 0, (size_t)NP * 4, stream);
  hipMemsetAsync(gpool, 0, 16384, stream);
  hipMemsetAsync(gcur, 0, 1024, stream);

  ngnn97_pre<<<899, 256, 0, stream>>>(ggc, wih, whh, bih, bhh, tfW, ztab, Ubt, Ub, Vbt, ztabh);
  ngnn97_g8<<<(NN + 255) / 256, 256, 0, stream>>>(n2s, s2g, g8);
  ngnn97_bucket<<<NBLK, 256, 0, stream>>>(g8, gcur, nlist);

  // CSR by dst
  const int* srcp = ei;
  const int* dstp = ei + EE;
  ngnn97_hist<<<(EE + 255) / 256, 256, 0, stream>>>(dstp, counts);
  ngnn97_red<<<NBLK, 256, 0, stream>>>(counts, bsum);
  ngnn97_scan1<<<1, 512, 0, stream>>>(bsum, boff);
  ngnn97_scan2<<<NBLK, 256, 0, stream>>>(counts, boff, rowp, curs);
  ngnn97_fill<<<(EE + 255) / 256, 256, 0, stream>>>(srcp, dstp, curs, srcs);
  // rowp[n]..rowp[n+1] bounds node n's incoming-edge list

  ngnn97_embed<<<(NN * 8 + 255) / 256, 256, 0, stream>>>(z, ztabh, xh0);

  unsigned short* xc = xh0;
  unsigned short* xn2 = xh1;
  for (int l = 0; l < 5; l++) {
    ngnn97_gru<<<(NN + 127) / 128, 256, 0, stream>>>(
        xc, xn2, rowp, srcs,
        Ubt + (size_t)l * 32768, Ub + (size_t)l * 256,
        Vbt + (size_t)(l < 4 ? l : 0) * 8192, tfb + (size_t)(l < 4 ? l : 0) * 64,
        z, ztabh + (size_t)(l < 4 ? l + 1 : 0) * 6400, (l < 4) ? 1 : 0);
    unsigned short* tmp = xc; xc = xn2; xn2 = tmp;
  }
  // final state in xc

  ngnn97_pool<<<1024, 256, 0, stream>>>(xc, nlist, gcur, gpool);
  ngnn97_head<<<1, 256, 0, stream>>>(gpool, W1, b1, W2, b2, W3, b3, out);
}